// Round 1
// baseline (688.963 us; speedup 1.0000x reference)
//
#include <hip/hip_runtime.h>
#include <hip/hip_bf16.h>

#define DEV __device__ __forceinline__

typedef __attribute__((ext_vector_type(4))) float f32x4;
typedef __attribute__((ext_vector_type(8))) __bf16 bf16x8;
typedef __attribute__((ext_vector_type(8))) unsigned short ushort8;

static constexpr int BATCH = 2, SEQ = 2048, DM = 1024, NH = 16, HDIM = 64;
static constexpr size_t XSZ = (size_t)BATCH * SEQ * DM;  // 4194304 elems per [4096,1024]

DEV unsigned short f2bf(float f) {
  union { float f; unsigned int u; } v; v.f = f;
  unsigned int r = (v.u + 0x7fffu + ((v.u >> 16) & 1u)) >> 16;  // RNE; inputs are finite
  return (unsigned short)r;
}

DEV bf16x8 ld8(const unsigned short* p) {
  return __builtin_bit_cast(bf16x8, *(const ushort8*)p);
}

DEV f32x4 mfma16(bf16x8 a, bf16x8 b, f32x4 c) {
  return __builtin_amdgcn_mfma_f32_16x16x32_bf16(a, b, c, 0, 0, 0);
}

// async global->LDS, 16B per lane; lds dest is wave-uniform base + lane*16
DEV void gll16(const unsigned short* g, unsigned short* l) {
  __builtin_amdgcn_global_load_lds(
      (__attribute__((address_space(1))) void*)(unsigned short*)g,
      (__attribute__((address_space(3))) void*)l, 16, 0, 0);
}

// ---------------------------------------------------------------- converts
__global__ __launch_bounds__(256)
void k_convert_x(const float* __restrict__ vis, const float* __restrict__ inff,
                 unsigned short* __restrict__ out) {
  const float* src = blockIdx.z ? inff : vis;
  unsigned short* dst = out + (size_t)blockIdx.z * XSZ;
  const size_t i = ((size_t)blockIdx.x * 256 + threadIdx.x) * 8;
  const float4 a = *(const float4*)(src + i);
  const float4 b = *(const float4*)(src + i + 4);
  ushort8 v;
  v[0] = f2bf(a.x); v[1] = f2bf(a.y); v[2] = f2bf(a.z); v[3] = f2bf(a.w);
  v[4] = f2bf(b.x); v[5] = f2bf(b.y); v[6] = f2bf(b.z); v[7] = f2bf(b.w);
  *(ushort8*)(dst + i) = v;
}

struct WPtrs { const float* w[8]; };

// W fp32 [K=1024][N=1024] row-major  ->  Wt bf16 [N][K] row-major
__global__ __launch_bounds__(256)
void k_convert_w(WPtrs p, unsigned short* __restrict__ wt) {
  const float* W = p.w[blockIdx.z];
  unsigned short* Wt = wt + (size_t)blockIdx.z * (1024 * 1024);
  const int k0 = blockIdx.y * 64, n0 = blockIdx.x * 64;
  __shared__ unsigned short t[64][68];
  const int tx = threadIdx.x & 15, ty = threadIdx.x >> 4;
#pragma unroll
  for (int i = 0; i < 4; ++i) {
    const int kr = ty * 4 + i;
    const float4 v = *(const float4*)(W + (size_t)(k0 + kr) * 1024 + n0 + tx * 4);
    t[kr][tx * 4 + 0] = f2bf(v.x); t[kr][tx * 4 + 1] = f2bf(v.y);
    t[kr][tx * 4 + 2] = f2bf(v.z); t[kr][tx * 4 + 3] = f2bf(v.w);
  }
  __syncthreads();
#pragma unroll
  for (int i = 0; i < 4; ++i) {
    const int nr = ty * 4 + i;
    ushort4 o;
    o.x = t[tx * 4 + 0][nr]; o.y = t[tx * 4 + 1][nr];
    o.z = t[tx * 4 + 2][nr]; o.w = t[tx * 4 + 3][nr];
    *(ushort4*)(Wt + (size_t)(n0 + nr) * 1024 + k0 + tx * 4) = o;
  }
}

// ---------------------------------------------------------------- GEMM
// C[4096,1024] = A[4096,1024](bf16) @ Wt[1024(n),1024(k)]^T(bf16) + bias
// MODE 0: out bf16 in heads layout [B,H,S,HD], value scaled by jb.scale
// MODE 1: out fp32 row-major [4096,1024]
struct GemmJob { const unsigned short* A; const unsigned short* W;
                 const float* bias; void* out; float scale; };
struct GemmJobs { GemmJob j[6]; };

template<int MODE>
__global__ __launch_bounds__(256)
void k_gemm(GemmJobs jobs) {
  const GemmJob jb = jobs.j[blockIdx.z];
  const int lane = threadIdx.x & 63, w = threadIdx.x >> 6;
  const int wr = w >> 1, wc = w & 1;               // 2x2 wave grid, 64x64 each
  const int r = lane & 15, g = lane >> 4;
  const int bm = blockIdx.y * 128, bn = blockIdx.x * 128;

  __shared__ __align__(16) unsigned short As[128 * 64];  // [row][k] swizzled
  __shared__ __align__(16) unsigned short Bs[128 * 64];

  // staging: inst q = w*4+j covers rows q*8..q*8+7 (128B/row = 8 chunks of 16B)
  // lane l -> row q*8 + (l>>3), lds chunk pos l&7; logical chunk = pos ^ (row&7)
  const int srow = lane >> 3;
  const int schunk = (lane & 7) ^ srow;
  const unsigned short* Ag = jb.A + (size_t)(bm + w * 32 + srow) * DM + schunk * 8;
  const unsigned short* Bg = jb.W + (size_t)(bn + w * 32 + srow) * DM + schunk * 8;

  f32x4 acc[4][4] = {};

  for (int kt = 0; kt < DM; kt += 64) {
#pragma unroll
    for (int j = 0; j < 4; ++j) {
      gll16(Ag + kt + j * 8 * DM, As + (w * 4 + j) * 512);
      gll16(Bg + kt + j * 8 * DM, Bs + (w * 4 + j) * 512);
    }
    __syncthreads();
#pragma unroll
    for (int kk = 0; kk < 2; ++kk) {
      bf16x8 a[4], b[4];
#pragma unroll
      for (int m = 0; m < 4; ++m) {
        const int row = wr * 64 + m * 16 + r;
        const int pos = (kk * 4 + g) ^ (row & 7);
        a[m] = ld8(As + row * 64 + pos * 8);
      }
#pragma unroll
      for (int n = 0; n < 4; ++n) {
        const int row = wc * 64 + n * 16 + r;
        const int pos = (kk * 4 + g) ^ (row & 7);
        b[n] = ld8(Bs + row * 64 + pos * 8);
      }
#pragma unroll
      for (int m = 0; m < 4; ++m)
#pragma unroll
        for (int n = 0; n < 4; ++n)
          acc[m][n] = mfma16(a[m], b[n], acc[m][n]);
    }
    __syncthreads();
  }

  // epilogue; C/D frag: row = 4*g + i, col = r (m89-verified)
  if (MODE == 0) {
    unsigned short* O = (unsigned short*)jb.out;
#pragma unroll
    for (int n = 0; n < 4; ++n) {
      const int nc = bn + wc * 64 + n * 16 + r;
      const float bv = jb.bias[nc];
      const int h = nc >> 6, hd = nc & 63;
#pragma unroll
      for (int m = 0; m < 4; ++m)
#pragma unroll
        for (int i = 0; i < 4; ++i) {
          const int mr = bm + wr * 64 + m * 16 + g * 4 + i;
          const int bb = mr >> 11, s = mr & 2047;
          O[((size_t)(bb * NH + h) * SEQ + s) * HDIM + hd] =
              f2bf((acc[m][n][i] + bv) * jb.scale);
        }
    }
  } else {
    float* O = (float*)jb.out;
#pragma unroll
    for (int n = 0; n < 4; ++n) {
      const int nc = bn + wc * 64 + n * 16 + r;
      const float bv = jb.bias[nc];
#pragma unroll
      for (int m = 0; m < 4; ++m)
#pragma unroll
        for (int i = 0; i < 4; ++i) {
          const int mr = bm + wr * 64 + m * 16 + g * 4 + i;
          O[(size_t)mr * DM + nc] = acc[m][n][i] + bv;
        }
    }
  }
}

// ---------------------------------------------------------------- V transpose
// V [B*H, S, HD] -> Vt [B*H, HD, S]  (bf16), so PV B-operand reads are contiguous
__global__ __launch_bounds__(256)
void k_transpose_v(const unsigned short* __restrict__ Vv, const unsigned short* __restrict__ Vi,
                   unsigned short* __restrict__ Vvt, unsigned short* __restrict__ Vit) {
  const unsigned short* src = blockIdx.z ? Vi : Vv;
  unsigned short* dst = blockIdx.z ? Vit : Vvt;
  const int bh = blockIdx.y;
  const int s0 = blockIdx.x * 64;
  __shared__ unsigned short t[64][68];
  const int tx = threadIdx.x & 15, ty = threadIdx.x >> 4;
#pragma unroll
  for (int i = 0; i < 4; ++i) {
    const int sr = ty * 4 + i;
    const ushort4 v = *(const ushort4*)(src + ((size_t)bh * SEQ + s0 + sr) * HDIM + tx * 4);
    t[sr][tx * 4 + 0] = v.x; t[sr][tx * 4 + 1] = v.y;
    t[sr][tx * 4 + 2] = v.z; t[sr][tx * 4 + 3] = v.w;
  }
  __syncthreads();
#pragma unroll
  for (int i = 0; i < 4; ++i) {
    const int dr = ty * 4 + i;  // hd
    ushort4 o;
    o.x = t[tx * 4 + 0][dr]; o.y = t[tx * 4 + 1][dr];
    o.z = t[tx * 4 + 2][dr]; o.w = t[tx * 4 + 3][dr];
    *(ushort4*)(dst + ((size_t)bh * HDIM + dr) * SEQ + s0 + tx * 4) = o;
  }
}

// ---------------------------------------------------------------- attention
// Per wave: 16 q-rows, online softmax, KV blocks of 32. Q pre-scaled by 1/8.
// Q,K: [B*H, S, 64] bf16; Vt: [B*H, 64, S] bf16; O: [B, S, D] bf16 (merged)
struct AttnJob { const unsigned short* Q; const unsigned short* K;
                 const unsigned short* Vt; unsigned short* O; };
struct AttnJobs { AttnJob j[2]; };

__global__ __launch_bounds__(256)
void k_attn(AttnJobs jobs) {
  const AttnJob jb = jobs.j[blockIdx.z];
  const int bh = blockIdx.y;
  const int lane = threadIdx.x & 63, w = threadIdx.x >> 6;
  const int r = lane & 15, g = lane >> 4;
  const int q0 = blockIdx.x * 64 + w * 16;
  const unsigned short* Qp = jb.Q + ((size_t)bh * SEQ + q0) * HDIM;
  const unsigned short* Kp = jb.K + (size_t)bh * SEQ * HDIM;
  const unsigned short* Vp = jb.Vt + (size_t)bh * HDIM * SEQ;

  const bf16x8 qf0 = ld8(Qp + r * 64 + g * 8);        // A-frag: row=r, k=8g+i
  const bf16x8 qf1 = ld8(Qp + r * 64 + 32 + g * 8);

  f32x4 o[4] = {};
  float mrow[4] = {-1e30f, -1e30f, -1e30f, -1e30f};
  float lrow[4] = {};

  // wave-private P buffer, row stride 48 ushorts (96B: 16B-aligned, 4-way max)
  __shared__ __align__(16) unsigned short plds[4][16 * 48];
  unsigned short* P = plds[w];

  for (int kv = 0; kv < SEQ; kv += 32) {
    const unsigned short* kp = Kp + (size_t)kv * HDIM;
    f32x4 s0 = {}, s1 = {};
    s0 = mfma16(qf0, ld8(kp + r * 64 + g * 8), s0);
    s0 = mfma16(qf1, ld8(kp + r * 64 + 32 + g * 8), s0);
    s1 = mfma16(qf0, ld8(kp + (16 + r) * 64 + g * 8), s1);
    s1 = mfma16(qf1, ld8(kp + (16 + r) * 64 + 32 + g * 8), s1);

    float mx[4], al[4], sm[4];
#pragma unroll
    for (int i = 0; i < 4; ++i) mx[i] = fmaxf(s0[i], s1[i]);
#pragma unroll
    for (int d = 1; d < 16; d <<= 1)
#pragma unroll
      for (int i = 0; i < 4; ++i) mx[i] = fmaxf(mx[i], __shfl_xor(mx[i], d, 64));
#pragma unroll
    for (int i = 0; i < 4; ++i) {
      const float mn = fmaxf(mrow[i], mx[i]);
      al[i] = __expf(mrow[i] - mn);
      mrow[i] = mn;
      s0[i] = __expf(s0[i] - mn);
      s1[i] = __expf(s1[i] - mn);
      sm[i] = s0[i] + s1[i];
    }
#pragma unroll
    for (int d = 1; d < 16; d <<= 1)
#pragma unroll
      for (int i = 0; i < 4; ++i) sm[i] += __shfl_xor(sm[i], d, 64);
#pragma unroll
    for (int i = 0; i < 4; ++i) lrow[i] = lrow[i] * al[i] + sm[i];
#pragma unroll
    for (int dt = 0; dt < 4; ++dt)
#pragma unroll
      for (int i = 0; i < 4; ++i) o[dt][i] *= al[i];

    // P: C-layout (row=4g+i, col=r) -> A-layout via wave-private LDS
#pragma unroll
    for (int i = 0; i < 4; ++i) {
      P[(4 * g + i) * 48 + r] = f2bf(s0[i]);
      P[(4 * g + i) * 48 + 16 + r] = f2bf(s1[i]);
    }
    asm volatile("s_waitcnt lgkmcnt(0)" ::: "memory");
    const bf16x8 pf = ld8(P + r * 48 + g * 8);        // A-frag: row=r, k=8g+i

    const unsigned short* vp = Vp + kv;
#pragma unroll
    for (int dt = 0; dt < 4; ++dt)                    // B-frag from Vt: n=dt*16+r, k=8g+i
      o[dt] = mfma16(pf, ld8(vp + (size_t)(dt * 16 + r) * SEQ + g * 8), o[dt]);
  }

  const int bb = bh >> 4, h = bh & 15;
#pragma unroll
  for (int dt = 0; dt < 4; ++dt)
#pragma unroll
    for (int i = 0; i < 4; ++i) {
      const int srow = q0 + 4 * g + i;
      jb.O[(size_t)(bb * SEQ + srow) * DM + h * HDIM + dt * 16 + r] =
          f2bf(o[dt][i] / lrow[i]);
    }
}

// ---------------------------------------------------------------- launch
extern "C" void kernel_launch(void* const* d_in, const int* in_sizes, int n_in,
                              void* d_out, int out_size, void* d_ws, size_t ws_size,
                              hipStream_t stream) {
  const float* vis = (const float*)d_in[0];
  const float* inff = (const float*)d_in[1];

  unsigned short* xbf  = (unsigned short*)d_ws;        // [2][4096][1024] bf16
  unsigned short* wt   = xbf + 2 * XSZ;                // 8 x [1024][1024] bf16 (transposed)
  unsigned short* Qv   = wt + (size_t)8 * 1024 * 1024; // each [B*H, S, HD]
  unsigned short* Kv   = Qv + XSZ;
  unsigned short* Vv   = Kv + XSZ;
  unsigned short* Qi   = Vv + XSZ;
  unsigned short* Ki   = Qi + XSZ;
  unsigned short* Vi   = Ki + XSZ;
  unsigned short* Vvt  = Vi + XSZ;                     // [B*H, HD, S]
  unsigned short* Vit  = Vvt + XSZ;
  unsigned short* atA  = Vit + XSZ;                    // softmax(Qv Ki^T) Vi, [B,S,D]
  unsigned short* atB  = atA + XSZ;                    // softmax(Qi Kv^T) Vv
  // total ws use: 117,440,512 bytes

  k_convert_x<<<dim3(2048, 1, 2), 256, 0, stream>>>(vis, inff, xbf);

  WPtrs wp;
  wp.w[0] = (const float*)d_in[2];  wp.w[1] = (const float*)d_in[4];
  wp.w[2] = (const float*)d_in[6];  wp.w[3] = (const float*)d_in[8];
  wp.w[4] = (const float*)d_in[10]; wp.w[5] = (const float*)d_in[12];
  wp.w[6] = (const float*)d_in[14]; wp.w[7] = (const float*)d_in[16];
  k_convert_w<<<dim3(16, 16, 8), 256, 0, stream>>>(wp, wt);

  const size_t WSZ = (size_t)1024 * 1024;
  const float sc = 0.125f;  // 1/sqrt(64), exact in bf16
  GemmJobs pj;
  pj.j[0] = { xbf,       wt + 0 * WSZ, (const float*)d_in[3],  (void*)Qv, sc };
  pj.j[1] = { xbf,       wt + 1 * WSZ, (const float*)d_in[5],  (void*)Kv, 1.f };
  pj.j[2] = { xbf,       wt + 2 * WSZ, (const float*)d_in[7],  (void*)Vv, 1.f };
  pj.j[3] = { xbf + XSZ, wt + 3 * WSZ, (const float*)d_in[9],  (void*)Qi, sc };
  pj.j[4] = { xbf + XSZ, wt + 4 * WSZ, (const float*)d_in[11], (void*)Ki, 1.f };
  pj.j[5] = { xbf + XSZ, wt + 5 * WSZ, (const float*)d_in[13], (void*)Vi, 1.f };
  k_gemm<0><<<dim3(8, 32, 6), 256, 0, stream>>>(pj);

  k_transpose_v<<<dim3(32, 32, 2), 256, 0, stream>>>(Vv, Vi, Vvt, Vit);

  AttnJobs aj;
  aj.j[0] = { Qv, Ki, Vit, atA };  // vis queries over inf K/V -> out_inf path
  aj.j[1] = { Qi, Kv, Vvt, atB };  // inf queries over vis K/V -> out_vis path
  k_attn<<<dim3(32, 32, 2), 256, 0, stream>>>(aj);

  GemmJobs oj;
  oj.j[0] = { atB, wt + 6 * WSZ, (const float*)d_in[15], d_out, 1.f };                      // out_vis
  oj.j[1] = { atA, wt + 7 * WSZ, (const float*)d_in[17], (void*)((float*)d_out + XSZ), 1.f }; // out_inf
  for (int z = 2; z < 6; ++z) oj.j[z] = oj.j[0];  // unused slots
  k_gemm<1><<<dim3(8, 32, 2), 256, 0, stream>>>(oj);
}

// Round 2
// 353.193 us; speedup vs baseline: 1.9507x; 1.9507x over previous
//
#include <hip/hip_runtime.h>
#include <hip/hip_bf16.h>

#define DEV __device__ __forceinline__

typedef __attribute__((ext_vector_type(4))) float f32x4;
typedef __attribute__((ext_vector_type(16))) float f32x16;
typedef __attribute__((ext_vector_type(8))) __bf16 bf16x8;
typedef __attribute__((ext_vector_type(8))) unsigned short ushort8;
typedef __attribute__((ext_vector_type(4))) unsigned int uint32x4;

static constexpr int BATCH = 2, SEQ = 2048, DM = 1024, NH = 16, HDIM = 64;
static constexpr size_t XSZ = (size_t)BATCH * SEQ * DM;  // 4194304 elems per [4096,1024]

DEV unsigned short f2bf(float f) {
  union { float f; unsigned int u; } v; v.f = f;
  unsigned int r = (v.u + 0x7fffu + ((v.u >> 16) & 1u)) >> 16;  // RNE; inputs are finite
  return (unsigned short)r;
}

DEV bf16x8 ld8(const unsigned short* p) {
  return __builtin_bit_cast(bf16x8, *(const ushort8*)p);
}

DEV f32x4 mfma16(bf16x8 a, bf16x8 b, f32x4 c) {
  return __builtin_amdgcn_mfma_f32_16x16x32_bf16(a, b, c, 0, 0, 0);
}
DEV f32x16 mfma32(bf16x8 a, bf16x8 b, f32x16 c) {
  return __builtin_amdgcn_mfma_f32_32x32x16_bf16(a, b, c, 0, 0, 0);
}

DEV unsigned cvtpk(float lo, float hi) {  // D[15:0]=bf16(lo), D[31:16]=bf16(hi)
  unsigned r;
  asm("v_cvt_pk_bf16_f32 %0, %1, %2" : "=v"(r) : "v"(lo), "v"(hi));
  return r;
}
DEV void plswap(unsigned& a, unsigned& b) {  // swap a.hi-lanes <-> b.lo-lanes
  asm("v_permlane32_swap_b32 %0, %1" : "+v"(a), "+v"(b));
}

// async global->LDS, 16B per lane; lds dest is wave-uniform base + lane*16
DEV void gll16(const unsigned short* g, unsigned short* l) {
  __builtin_amdgcn_global_load_lds(
      (__attribute__((address_space(1))) void*)(unsigned short*)g,
      (__attribute__((address_space(3))) void*)l, 16, 0, 0);
}

// ---------------------------------------------------------------- converts
__global__ __launch_bounds__(256)
void k_convert_x(const float* __restrict__ vis, const float* __restrict__ inff,
                 unsigned short* __restrict__ out) {
  const float* src = blockIdx.z ? inff : vis;
  unsigned short* dst = out + (size_t)blockIdx.z * XSZ;
  const size_t i = ((size_t)blockIdx.x * 256 + threadIdx.x) * 8;
  const float4 a = *(const float4*)(src + i);
  const float4 b = *(const float4*)(src + i + 4);
  ushort8 v;
  v[0] = f2bf(a.x); v[1] = f2bf(a.y); v[2] = f2bf(a.z); v[3] = f2bf(a.w);
  v[4] = f2bf(b.x); v[5] = f2bf(b.y); v[6] = f2bf(b.z); v[7] = f2bf(b.w);
  *(ushort8*)(dst + i) = v;
}

struct WPtrs { const float* w[8]; };

// W fp32 [K=1024][N=1024] row-major  ->  Wt bf16 [N][K] row-major
__global__ __launch_bounds__(256)
void k_convert_w(WPtrs p, unsigned short* __restrict__ wt) {
  const float* W = p.w[blockIdx.z];
  unsigned short* Wt = wt + (size_t)blockIdx.z * (1024 * 1024);
  const int k0 = blockIdx.y * 64, n0 = blockIdx.x * 64;
  __shared__ unsigned short t[64][68];
  const int tx = threadIdx.x & 15, ty = threadIdx.x >> 4;
#pragma unroll
  for (int i = 0; i < 4; ++i) {
    const int kr = ty * 4 + i;
    const float4 v = *(const float4*)(W + (size_t)(k0 + kr) * 1024 + n0 + tx * 4);
    t[kr][tx * 4 + 0] = f2bf(v.x); t[kr][tx * 4 + 1] = f2bf(v.y);
    t[kr][tx * 4 + 2] = f2bf(v.z); t[kr][tx * 4 + 3] = f2bf(v.w);
  }
  __syncthreads();
#pragma unroll
  for (int i = 0; i < 4; ++i) {
    const int nr = ty * 4 + i;
    ushort4 o;
    o.x = t[tx * 4 + 0][nr]; o.y = t[tx * 4 + 1][nr];
    o.z = t[tx * 4 + 2][nr]; o.w = t[tx * 4 + 3][nr];
    *(ushort4*)(Wt + (size_t)(n0 + nr) * 1024 + k0 + tx * 4) = o;
  }
}

// ---------------------------------------------------------------- GEMM
// C[4096,1024] = A[4096,1024](bf16) @ Wt[1024(n),1024(k)]^T(bf16) + bias
struct GemmJob { const unsigned short* A; const unsigned short* W;
                 const float* bias; void* out; float scale; };
struct GemmJobs { GemmJob j[6]; };

template<int MODE>
__global__ __launch_bounds__(256)
void k_gemm(GemmJobs jobs) {
  const GemmJob jb = jobs.j[blockIdx.z];
  const int lane = threadIdx.x & 63, w = threadIdx.x >> 6;
  const int wr = w >> 1, wc = w & 1;               // 2x2 wave grid, 64x64 each
  const int r = lane & 15, g = lane >> 4;
  const int bm = blockIdx.y * 128, bn = blockIdx.x * 128;

  __shared__ __align__(16) unsigned short As[128 * 64];  // [row][k] swizzled
  __shared__ __align__(16) unsigned short Bs[128 * 64];

  const int srow = lane >> 3;
  const int schunk = (lane & 7) ^ srow;
  const unsigned short* Ag = jb.A + (size_t)(bm + w * 32 + srow) * DM + schunk * 8;
  const unsigned short* Bg = jb.W + (size_t)(bn + w * 32 + srow) * DM + schunk * 8;

  f32x4 acc[4][4] = {};

  for (int kt = 0; kt < DM; kt += 64) {
#pragma unroll
    for (int j = 0; j < 4; ++j) {
      gll16(Ag + kt + j * 8 * DM, As + (w * 4 + j) * 512);
      gll16(Bg + kt + j * 8 * DM, Bs + (w * 4 + j) * 512);
    }
    __syncthreads();
#pragma unroll
    for (int kk = 0; kk < 2; ++kk) {
      bf16x8 a[4], b[4];
#pragma unroll
      for (int m = 0; m < 4; ++m) {
        const int row = wr * 64 + m * 16 + r;
        const int pos = (kk * 4 + g) ^ (row & 7);
        a[m] = ld8(As + row * 64 + pos * 8);
      }
#pragma unroll
      for (int n = 0; n < 4; ++n) {
        const int row = wc * 64 + n * 16 + r;
        const int pos = (kk * 4 + g) ^ (row & 7);
        b[n] = ld8(Bs + row * 64 + pos * 8);
      }
#pragma unroll
      for (int m = 0; m < 4; ++m)
#pragma unroll
        for (int n = 0; n < 4; ++n)
          acc[m][n] = mfma16(a[m], b[n], acc[m][n]);
    }
    __syncthreads();
  }

  if (MODE == 0) {
    unsigned short* O = (unsigned short*)jb.out;
#pragma unroll
    for (int n = 0; n < 4; ++n) {
      const int nc = bn + wc * 64 + n * 16 + r;
      const float bv = jb.bias[nc];
      const int h = nc >> 6, hd = nc & 63;
#pragma unroll
      for (int m = 0; m < 4; ++m)
#pragma unroll
        for (int i = 0; i < 4; ++i) {
          const int mr = bm + wr * 64 + m * 16 + g * 4 + i;
          const int bb = mr >> 11, s = mr & 2047;
          O[((size_t)(bb * NH + h) * SEQ + s) * HDIM + hd] =
              f2bf((acc[m][n][i] + bv) * jb.scale);
        }
    }
  } else {
    float* O = (float*)jb.out;
#pragma unroll
    for (int n = 0; n < 4; ++n) {
      const int nc = bn + wc * 64 + n * 16 + r;
      const float bv = jb.bias[nc];
#pragma unroll
      for (int m = 0; m < 4; ++m)
#pragma unroll
        for (int i = 0; i < 4; ++i) {
          const int mr = bm + wr * 64 + m * 16 + g * 4 + i;
          O[(size_t)mr * DM + nc] = acc[m][n][i] + bv;
        }
    }
  }
}

// ---------------------------------------------------------------- V transpose
// V [B*H, S, HD] -> Vt [B*H, HD, S]  (bf16)
__global__ __launch_bounds__(256)
void k_transpose_v(const unsigned short* __restrict__ Vv, const unsigned short* __restrict__ Vi,
                   unsigned short* __restrict__ Vvt, unsigned short* __restrict__ Vit) {
  const unsigned short* src = blockIdx.z ? Vi : Vv;
  unsigned short* dst = blockIdx.z ? Vit : Vvt;
  const int bh = blockIdx.y;
  const int s0 = blockIdx.x * 64;
  __shared__ unsigned short t[64][68];
  const int tx = threadIdx.x & 15, ty = threadIdx.x >> 4;
#pragma unroll
  for (int i = 0; i < 4; ++i) {
    const int sr = ty * 4 + i;
    const ushort4 v = *(const ushort4*)(src + ((size_t)bh * SEQ + s0 + sr) * HDIM + tx * 4);
    t[sr][tx * 4 + 0] = v.x; t[sr][tx * 4 + 1] = v.y;
    t[sr][tx * 4 + 2] = v.z; t[sr][tx * 4 + 3] = v.w;
  }
  __syncthreads();
#pragma unroll
  for (int i = 0; i < 4; ++i) {
    const int dr = ty * 4 + i;  // hd
    ushort4 o;
    o.x = t[tx * 4 + 0][dr]; o.y = t[tx * 4 + 1][dr];
    o.z = t[tx * 4 + 2][dr]; o.w = t[tx * 4 + 3][dr];
    *(ushort4*)(dst + ((size_t)bh * HDIM + dr) * SEQ + s0 + tx * 4) = o;
  }
}

// ---------------------------------------------------------------- attention
// 4 waves/block, 32 q-rows/wave, KVBLK=64, swapped QK^T and PV (32x32x16 MFMA).
// S^T = K·Q^T : lane's 32 score regs all for q-row = lane&31.
// O^T = V^T·P : lane's 32 O regs all for the same q-row.
// Q pre-scaled by 1/8. K LDS [64][64] and Vt LDS [64][64], slot^=(row&7) swizzle,
// staged via pre-swizzled-source global_load_lds (rule 21), double-buffered.
struct AttnJob { const unsigned short* Q; const unsigned short* K;
                 const unsigned short* Vt; unsigned short* O; };
struct AttnJobs { AttnJob j[2]; };

__global__ __launch_bounds__(256)
void k_attn(AttnJobs jobs) {
  const AttnJob jb = jobs.j[blockIdx.z];
  const int bh = blockIdx.y;
  const int lane = threadIdx.x & 63, w = threadIdx.x >> 6;
  const int q5 = lane & 31, hi = lane >> 5;
  const int qrow = blockIdx.x * 128 + w * 32 + q5;

  const unsigned short* Qp = jb.Q + (size_t)bh * SEQ * HDIM;
  const unsigned short* Kp = jb.K + (size_t)bh * SEQ * HDIM;
  const unsigned short* Vp = jb.Vt + (size_t)bh * HDIM * SEQ;

  __shared__ __align__(16) unsigned short Ks[2][64 * 64];
  __shared__ __align__(16) unsigned short Vs[2][64 * 64];

  // Q fragments (B-operand): qf[c] = Q[qrow][c*16 + hi*8 .. +7]
  bf16x8 qf[4];
#pragma unroll
  for (int c = 0; c < 4; ++c)
    qf[c] = ld8(Qp + (size_t)qrow * HDIM + c * 16 + hi * 8);

  // staging constants: lane covers row (l>>3) of its 8-row group, slot l&7,
  // source chunk = slot ^ (row&7)  (pre-swizzled source, linear LDS dest)
  const int srow = lane >> 3;
  const int sslot = lane & 7;

  auto stage = [&](int buf, int kv0) {
#pragma unroll
    for (int j = 0; j < 2; ++j) {
      const int row = j * 32 + w * 8 + srow;          // 0..63
      const int u = sslot ^ (row & 7);
      gll16(Kp + (size_t)(kv0 + row) * HDIM + u * 8, Ks[buf] + (j * 32 + w * 8) * 64);
      gll16(Vp + (size_t)row * SEQ + kv0 + u * 8,    Vs[buf] + (j * 32 + w * 8) * 64);
    }
  };

  f32x16 o0 = {}, o1 = {};
  float mrow = -1e30f, lrow = 0.f;
  const int swz = q5 & 7;

  stage(0, 0);
  __syncthreads();

  for (int t = 0; t < SEQ / 64; ++t) {
    const int cur = t & 1;
    if (t + 1 < SEQ / 64) stage(cur ^ 1, (t + 1) * 64);

    // ---- QK^T (swapped): S^T[kv][q], two 32-kv tiles
    f32x16 s0 = {}, s1 = {};
    __builtin_amdgcn_s_setprio(1);
#pragma unroll
    for (int c = 0; c < 4; ++c) {
      const int sl = ((2 * c + hi) ^ swz) * 8;
      s0 = mfma32(ld8(Ks[cur] + q5 * 64 + sl), qf[c], s0);
      s1 = mfma32(ld8(Ks[cur] + (32 + q5) * 64 + sl), qf[c], s1);
    }
    __builtin_amdgcn_s_setprio(0);

    // ---- row max (in-register tree + 1 partner exchange)
    float tm[8];
#pragma unroll
    for (int r = 0; r < 8; ++r)
      tm[r] = fmaxf(fmaxf(s0[r], s0[r + 8]), fmaxf(s1[r], s1[r + 8]));
    float mx = fmaxf(fmaxf(fmaxf(tm[0], tm[1]), fmaxf(tm[2], tm[3])),
                     fmaxf(fmaxf(tm[4], tm[5]), fmaxf(tm[6], tm[7])));
    mx = fmaxf(mx, __shfl_xor(mx, 32, 64));

    // ---- defer-max (T13, THR=8)
    if (!__all(mx <= mrow + 8.f)) {
      const float mn = fmaxf(mx, mrow);
      const float al = __expf(mrow - mn);
      mrow = mn;
      lrow *= al;
#pragma unroll
      for (int r = 0; r < 16; ++r) { o0[r] *= al; o1[r] *= al; }
    }

    // ---- P = exp(S - m), partial row-sum (own 32 kv only)
    float ps = 0.f, ps2 = 0.f;
#pragma unroll
    for (int r = 0; r < 16; ++r) {
      s0[r] = __expf(s0[r] - mrow); ps += s0[r];
      s1[r] = __expf(s1[r] - mrow); ps2 += s1[r];
    }
    lrow += ps + ps2;

    // ---- pack P to bf16 words (T12)
    unsigned pk0[8], pk1[8];
#pragma unroll
    for (int ww = 0; ww < 8; ++ww) {
      pk0[ww] = cvtpk(s0[2 * ww], s0[2 * ww + 1]);
      pk1[ww] = cvtpk(s1[2 * ww], s1[2 * ww + 1]);
    }

    // ---- PV (swapped): O^T += V^T · P
    __builtin_amdgcn_s_setprio(1);
#pragma unroll
    for (int c = 0; c < 4; ++c) {
      const int wb = 4 * (c & 1);
      unsigned a0 = (c < 2) ? pk0[wb + 0] : pk1[wb + 0];
      unsigned a1 = (c < 2) ? pk0[wb + 1] : pk1[wb + 1];
      unsigned b0 = (c < 2) ? pk0[wb + 2] : pk1[wb + 2];
      unsigned b1 = (c < 2) ? pk0[wb + 3] : pk1[wb + 3];
      plswap(a0, b0);  // a: frag word0, b: frag word2 (both halves correct)
      plswap(a1, b1);  // a: frag word1, b: frag word3
      uint32x4 fw = {a0, a1, b0, b1};
      const bf16x8 pf = __builtin_bit_cast(bf16x8, fw);
      const int sl = ((2 * c + hi) ^ swz) * 8;
      o0 = mfma32(ld8(Vs[cur] + q5 * 64 + sl), pf, o0);
      o1 = mfma32(ld8(Vs[cur] + (32 + q5) * 64 + sl), pf, o1);
    }
    __builtin_amdgcn_s_setprio(0);

    __syncthreads();
  }

  // ---- epilogue: combine partner l, normalize, write O[q][d]
  const float ltot = lrow + __shfl_xor(lrow, 32, 64);
  const float inv = 1.f / ltot;
  const int bb = bh >> 4, h = bh & 15;
  unsigned short* Ob = jb.O + ((size_t)bb * SEQ + qrow) * DM + h * HDIM;

  auto storeO = [&](const f32x16 oo, int dbase) {
#pragma unroll
    for (int g4 = 0; g4 < 4; ++g4) {
      ushort4 pv;
      pv.x = f2bf(oo[4 * g4 + 0] * inv);
      pv.y = f2bf(oo[4 * g4 + 1] * inv);
      pv.z = f2bf(oo[4 * g4 + 2] * inv);
      pv.w = f2bf(oo[4 * g4 + 3] * inv);
      *(ushort4*)(Ob + dbase + 8 * g4 + 4 * hi) = pv;  // d = dbase+8*g4+4*hi+i
    }
  };
  storeO(o0, 0);
  storeO(o1, 32);
}

// ---------------------------------------------------------------- launch
extern "C" void kernel_launch(void* const* d_in, const int* in_sizes, int n_in,
                              void* d_out, int out_size, void* d_ws, size_t ws_size,
                              hipStream_t stream) {
  const float* vis = (const float*)d_in[0];
  const float* inff = (const float*)d_in[1];

  unsigned short* xbf  = (unsigned short*)d_ws;        // [2][4096][1024] bf16
  unsigned short* wt   = xbf + 2 * XSZ;                // 8 x [1024][1024] bf16 (transposed)
  unsigned short* Qv   = wt + (size_t)8 * 1024 * 1024; // each [B*H, S, HD]
  unsigned short* Kv   = Qv + XSZ;
  unsigned short* Vv   = Kv + XSZ;
  unsigned short* Qi   = Vv + XSZ;
  unsigned short* Ki   = Qi + XSZ;
  unsigned short* Vi   = Ki + XSZ;
  unsigned short* Vvt  = Vi + XSZ;                     // [B*H, HD, S]
  unsigned short* Vit  = Vvt + XSZ;
  unsigned short* atA  = Vit + XSZ;                    // softmax(Qv Ki^T) Vi, [B,S,D]
  unsigned short* atB  = atA + XSZ;                    // softmax(Qi Kv^T) Vv

  k_convert_x<<<dim3(2048, 1, 2), 256, 0, stream>>>(vis, inff, xbf);

  WPtrs wp;
  wp.w[0] = (const float*)d_in[2];  wp.w[1] = (const float*)d_in[4];
  wp.w[2] = (const float*)d_in[6];  wp.w[3] = (const float*)d_in[8];
  wp.w[4] = (const float*)d_in[10]; wp.w[5] = (const float*)d_in[12];
  wp.w[6] = (const float*)d_in[14]; wp.w[7] = (const float*)d_in[16];
  k_convert_w<<<dim3(16, 16, 8), 256, 0, stream>>>(wp, wt);

  const size_t WSZ = (size_t)1024 * 1024;
  const float sc = 0.125f;  // 1/sqrt(64), exact in bf16
  GemmJobs pj;
  pj.j[0] = { xbf,       wt + 0 * WSZ, (const float*)d_in[3],  (void*)Qv, sc };
  pj.j[1] = { xbf,       wt + 1 * WSZ, (const float*)d_in[5],  (void*)Kv, 1.f };
  pj.j[2] = { xbf,       wt + 2 * WSZ, (const float*)d_in[7],  (void*)Vv, 1.f };
  pj.j[3] = { xbf + XSZ, wt + 3 * WSZ, (const float*)d_in[9],  (void*)Qi, sc };
  pj.j[4] = { xbf + XSZ, wt + 4 * WSZ, (const float*)d_in[11], (void*)Ki, 1.f };
  pj.j[5] = { xbf + XSZ, wt + 5 * WSZ, (const float*)d_in[13], (void*)Vi, 1.f };
  k_gemm<0><<<dim3(8, 32, 6), 256, 0, stream>>>(pj);

  k_transpose_v<<<dim3(32, 32, 2), 256, 0, stream>>>(Vv, Vi, Vvt, Vit);

  AttnJobs aj;
  aj.j[0] = { Qv, Ki, Vit, atA };  // vis queries over inf K/V -> out_inf path
  aj.j[1] = { Qi, Kv, Vvt, atB };  // inf queries over vis K/V -> out_vis path
  k_attn<<<dim3(16, 32, 2), 256, 0, stream>>>(aj);

  GemmJobs oj;
  oj.j[0] = { atB, wt + 6 * WSZ, (const float*)d_in[15], d_out, 1.f };                      // out_vis
  oj.j[1] = { atA, wt + 7 * WSZ, (const float*)d_in[17], (void*)((float*)d_out + XSZ), 1.f }; // out_inf
  for (int z = 2; z < 6; ++z) oj.j[z] = oj.j[0];  // unused slots
  k_gemm<1><<<dim3(8, 32, 2), 256, 0, stream>>>(oj);
}

// Round 3
// 324.739 us; speedup vs baseline: 2.1216x; 1.0876x over previous
//
#include <hip/hip_runtime.h>
#include <hip/hip_bf16.h>

#define DEV __device__ __forceinline__

typedef __attribute__((ext_vector_type(4))) float f32x4;
typedef __attribute__((ext_vector_type(16))) float f32x16;
typedef __attribute__((ext_vector_type(8))) __bf16 bf16x8;
typedef __attribute__((ext_vector_type(8))) unsigned short ushort8;
typedef __attribute__((ext_vector_type(4))) unsigned int uint32x4;

static constexpr int BATCH = 2, SEQ = 2048, DM = 1024, NH = 16, HDIM = 64;
static constexpr size_t XSZ = (size_t)BATCH * SEQ * DM;  // 4194304 elems per [4096,1024]

DEV unsigned short f2bf(float f) {
  union { float f; unsigned int u; } v; v.f = f;
  unsigned int r = (v.u + 0x7fffu + ((v.u >> 16) & 1u)) >> 16;  // RNE; inputs are finite
  return (unsigned short)r;
}

DEV bf16x8 ld8(const unsigned short* p) {
  return __builtin_bit_cast(bf16x8, *(const ushort8*)p);
}

DEV f32x4 mfma16(bf16x8 a, bf16x8 b, f32x4 c) {
  return __builtin_amdgcn_mfma_f32_16x16x32_bf16(a, b, c, 0, 0, 0);
}
DEV f32x16 mfma32(bf16x8 a, bf16x8 b, f32x16 c) {
  return __builtin_amdgcn_mfma_f32_32x32x16_bf16(a, b, c, 0, 0, 0);
}

DEV unsigned cvtpk(float lo, float hi) {  // D[15:0]=bf16(lo), D[31:16]=bf16(hi)
  unsigned r;
  asm("v_cvt_pk_bf16_f32 %0, %1, %2" : "=v"(r) : "v"(lo), "v"(hi));
  return r;
}
DEV void plswap(unsigned& a, unsigned& b) {  // swap a.hi-lanes <-> b.lo-lanes
  asm("v_permlane32_swap_b32 %0, %1" : "+v"(a), "+v"(b));
}

// async global->LDS, 16B per lane; lds dest is wave-uniform base + lane*16
DEV void gll16(const unsigned short* g, unsigned short* l) {
  __builtin_amdgcn_global_load_lds(
      (__attribute__((address_space(1))) void*)(unsigned short*)g,
      (__attribute__((address_space(3))) void*)l, 16, 0, 0);
}

// ---------------------------------------------------------------- converts
__global__ __launch_bounds__(256)
void k_convert_x(const float* __restrict__ vis, const float* __restrict__ inff,
                 unsigned short* __restrict__ out) {
  const float* src = blockIdx.z ? inff : vis;
  unsigned short* dst = out + (size_t)blockIdx.z * XSZ;
  const size_t i = ((size_t)blockIdx.x * 256 + threadIdx.x) * 8;
  const float4 a = *(const float4*)(src + i);
  const float4 b = *(const float4*)(src + i + 4);
  ushort8 v;
  v[0] = f2bf(a.x); v[1] = f2bf(a.y); v[2] = f2bf(a.z); v[3] = f2bf(a.w);
  v[4] = f2bf(b.x); v[5] = f2bf(b.y); v[6] = f2bf(b.z); v[7] = f2bf(b.w);
  *(ushort8*)(dst + i) = v;
}

struct WPtrs { const float* w[8]; };

// W fp32 [K=1024][N=1024] row-major  ->  Wt bf16 [N][K] row-major
__global__ __launch_bounds__(256)
void k_convert_w(WPtrs p, unsigned short* __restrict__ wt) {
  const float* W = p.w[blockIdx.z];
  unsigned short* Wt = wt + (size_t)blockIdx.z * (1024 * 1024);
  const int k0 = blockIdx.y * 64, n0 = blockIdx.x * 64;
  __shared__ unsigned short t[64][68];
  const int tx = threadIdx.x & 15, ty = threadIdx.x >> 4;
#pragma unroll
  for (int i = 0; i < 4; ++i) {
    const int kr = ty * 4 + i;
    const float4 v = *(const float4*)(W + (size_t)(k0 + kr) * 1024 + n0 + tx * 4);
    t[kr][tx * 4 + 0] = f2bf(v.x); t[kr][tx * 4 + 1] = f2bf(v.y);
    t[kr][tx * 4 + 2] = f2bf(v.z); t[kr][tx * 4 + 3] = f2bf(v.w);
  }
  __syncthreads();
#pragma unroll
  for (int i = 0; i < 4; ++i) {
    const int nr = ty * 4 + i;
    ushort4 o;
    o.x = t[tx * 4 + 0][nr]; o.y = t[tx * 4 + 1][nr];
    o.z = t[tx * 4 + 2][nr]; o.w = t[tx * 4 + 3][nr];
    *(ushort4*)(Wt + (size_t)(n0 + nr) * 1024 + k0 + tx * 4) = o;
  }
}

// ---------------------------------------------------------------- GEMM
// C[4096,1024] = A[4096,1024](bf16) @ Wt[1024(n),1024(k)]^T(bf16) + bias
// mode 0: bf16 heads [B,H,S,HD] (value * scale)   (Q, K)
// mode 2: bf16 heads transposed [B,H,HD,S]        (V)
// mode 1: fp32 row-major [4096,1024]              (O-proj)
struct GemmJob { const unsigned short* A; const unsigned short* W;
                 const float* bias; void* out; float scale; int mode; };
struct GemmJobs { GemmJob j[6]; };

__global__ __launch_bounds__(256)
void k_gemm(GemmJobs jobs) {
  const GemmJob jb = jobs.j[blockIdx.z];
  const int lane = threadIdx.x & 63, w = threadIdx.x >> 6;
  const int wr = w >> 1, wc = w & 1;               // 2x2 wave grid, 64x64 each
  const int r = lane & 15, g = lane >> 4;

  // XCD-chunked bijective swizzle (grid x=8, y=32): each XCD owns 4 contiguous
  // m-tiles (A-panel reuse in its private L2).
  const int nid = blockIdx.x + (blockIdx.y << 3);        // 0..255
  const int bxs = nid >> 5;                              // n-tile 0..7
  const int bys = ((nid & 7) << 2) + ((nid >> 3) & 3);   // m-tile 0..31
  const int bm = bys * 128, bn = bxs * 128;

  __shared__ __align__(16) unsigned short As[128 * 64];  // [row][k] swizzled
  __shared__ __align__(16) unsigned short Bs[128 * 64];

  const int srow = lane >> 3;
  const int schunk = (lane & 7) ^ srow;
  const unsigned short* Ag = jb.A + (size_t)(bm + w * 32 + srow) * DM + schunk * 8;
  const unsigned short* Bg = jb.W + (size_t)(bn + w * 32 + srow) * DM + schunk * 8;

  f32x4 acc[4][4] = {};

  for (int kt = 0; kt < DM; kt += 64) {
#pragma unroll
    for (int j = 0; j < 4; ++j) {
      gll16(Ag + kt + j * 8 * DM, As + (w * 4 + j) * 512);
      gll16(Bg + kt + j * 8 * DM, Bs + (w * 4 + j) * 512);
    }
    __syncthreads();
#pragma unroll
    for (int kk = 0; kk < 2; ++kk) {
      bf16x8 a[4], b[4];
#pragma unroll
      for (int m = 0; m < 4; ++m) {
        const int row = wr * 64 + m * 16 + r;
        const int pos = (kk * 4 + g) ^ (row & 7);
        a[m] = ld8(As + row * 64 + pos * 8);
      }
#pragma unroll
      for (int n = 0; n < 4; ++n) {
        const int row = wc * 64 + n * 16 + r;
        const int pos = (kk * 4 + g) ^ (row & 7);
        b[n] = ld8(Bs + row * 64 + pos * 8);
      }
#pragma unroll
      for (int m = 0; m < 4; ++m)
#pragma unroll
        for (int n = 0; n < 4; ++n)
          acc[m][n] = mfma16(a[m], b[n], acc[m][n]);
    }
    __syncthreads();
  }

  // epilogue; C/D frag: row = 4*g + i, col = r (m89-verified)
  if (jb.mode == 0) {
    unsigned short* O = (unsigned short*)jb.out;
#pragma unroll
    for (int n = 0; n < 4; ++n) {
      const int nc = bn + wc * 64 + n * 16 + r;
      const float bv = jb.bias[nc];
      const int h = nc >> 6, hd = nc & 63;
#pragma unroll
      for (int m = 0; m < 4; ++m)
#pragma unroll
        for (int i = 0; i < 4; ++i) {
          const int mr = bm + wr * 64 + m * 16 + g * 4 + i;
          const int bb = mr >> 11, s = mr & 2047;
          O[((size_t)(bb * NH + h) * SEQ + s) * HDIM + hd] =
              f2bf((acc[m][n][i] + bv) * jb.scale);
        }
    }
  } else if (jb.mode == 2) {
    unsigned short* O = (unsigned short*)jb.out;
#pragma unroll
    for (int n = 0; n < 4; ++n) {
      const int nc = bn + wc * 64 + n * 16 + r;
      const float bv = jb.bias[nc];
      const int h = nc >> 6, hd = nc & 63;
#pragma unroll
      for (int m = 0; m < 4; ++m) {
        const int mr = bm + wr * 64 + m * 16 + g * 4;   // quad-aligned s
        const int bb = mr >> 11, s = mr & 2047;
        ushort4 pv;
        pv.x = f2bf(acc[m][n][0] + bv);
        pv.y = f2bf(acc[m][n][1] + bv);
        pv.z = f2bf(acc[m][n][2] + bv);
        pv.w = f2bf(acc[m][n][3] + bv);
        *(ushort4*)(O + ((size_t)(bb * NH + h) * HDIM + hd) * SEQ + s) = pv;
      }
    }
  } else {
    float* O = (float*)jb.out;
#pragma unroll
    for (int n = 0; n < 4; ++n) {
      const int nc = bn + wc * 64 + n * 16 + r;
      const float bv = jb.bias[nc];
#pragma unroll
      for (int m = 0; m < 4; ++m)
#pragma unroll
        for (int i = 0; i < 4; ++i) {
          const int mr = bm + wr * 64 + m * 16 + g * 4 + i;
          O[(size_t)mr * DM + nc] = acc[m][n][i] + bv;
        }
    }
  }
}

// ---------------------------------------------------------------- attention
// 4 waves/block, 32 q-rows/wave, KVBLK=64, swapped QK^T and PV (32x32x16 MFMA).
// S' = S*log2e (log2e/8 folded into Q projection): softmax is native exp2.
// Row-sum l computed by ones-MFMA (layout-proof), no cross-lane reduction.
struct AttnJob { const unsigned short* Q; const unsigned short* K;
                 const unsigned short* Vt; unsigned short* O; };
struct AttnJobs { AttnJob j[2]; };

__global__ __launch_bounds__(256)
void k_attn(AttnJobs jobs) {
  const AttnJob jb = jobs.j[blockIdx.z];
  // XCD-chunked swizzle (grid x=16, y=32): each XCD owns 4 contiguous bh
  // so its private L2 holds just those K/V panels.
  const int nid = blockIdx.x + (blockIdx.y << 4);        // 0..511
  const int bx = nid >> 5;                               // q-tile 0..15
  const int bh = ((nid & 7) << 2) + ((nid >> 3) & 3);    // bh 0..31
  const int lane = threadIdx.x & 63, w = threadIdx.x >> 6;
  const int q5 = lane & 31, hi = lane >> 5;
  const int qrow = bx * 128 + w * 32 + q5;

  const unsigned short* Qp = jb.Q + (size_t)bh * SEQ * HDIM;
  const unsigned short* Kp = jb.K + (size_t)bh * SEQ * HDIM;
  const unsigned short* Vp = jb.Vt + (size_t)bh * HDIM * SEQ;

  __shared__ __align__(16) unsigned short Ks[2][64 * 64];
  __shared__ __align__(16) unsigned short Vs[2][64 * 64];

  // Q fragments (B-operand): qf[c] = Q[qrow][c*16 + hi*8 .. +7]
  bf16x8 qf[4];
#pragma unroll
  for (int c = 0; c < 4; ++c)
    qf[c] = ld8(Qp + (size_t)qrow * HDIM + c * 16 + hi * 8);

  // ones A-fragment for the row-sum MFMA (value layout-independent)
  ushort8 ov; 
#pragma unroll
  for (int i = 0; i < 8; ++i) ov[i] = 0x3f80;  // bf16 1.0
  const bf16x8 onesb = __builtin_bit_cast(bf16x8, ov);

  const int srow = lane >> 3;
  const int sslot = lane & 7;

  auto stage = [&](int buf, int kv0) {
#pragma unroll
    for (int j = 0; j < 2; ++j) {
      const int row = j * 32 + w * 8 + srow;          // 0..63
      const int u = sslot ^ (row & 7);
      gll16(Kp + (size_t)(kv0 + row) * HDIM + u * 8, Ks[buf] + (j * 32 + w * 8) * 64);
      gll16(Vp + (size_t)row * SEQ + kv0 + u * 8,    Vs[buf] + (j * 32 + w * 8) * 64);
    }
  };

  f32x16 o0 = {}, o1 = {}, lsum = {};
  float mrow = -1e30f;
  const int swz = q5 & 7;

  stage(0, 0);
  __syncthreads();

  for (int t = 0; t < SEQ / 64; ++t) {
    const int cur = t & 1;
    if (t + 1 < SEQ / 64) stage(cur ^ 1, (t + 1) * 64);

    // ---- QK^T (swapped): S'^T[kv][q], two 32-kv tiles
    f32x16 s0 = {}, s1 = {};
    __builtin_amdgcn_s_setprio(1);
#pragma unroll
    for (int c = 0; c < 4; ++c) {
      const int sl = ((2 * c + hi) ^ swz) * 8;
      s0 = mfma32(ld8(Ks[cur] + q5 * 64 + sl), qf[c], s0);
      s1 = mfma32(ld8(Ks[cur] + (32 + q5) * 64 + sl), qf[c], s1);
    }
    __builtin_amdgcn_s_setprio(0);

    // ---- row max (in-register tree + 1 partner exchange); max3-friendly nesting
    float tm[8];
#pragma unroll
    for (int r = 0; r < 8; ++r)
      tm[r] = fmaxf(fmaxf(s0[r], s0[r + 8]), fmaxf(s1[r], s1[r + 8]));
    float mx = fmaxf(fmaxf(fmaxf(tm[0], tm[1]), tm[2]),
                     fmaxf(fmaxf(tm[3], tm[4]), fmaxf(fmaxf(tm[5], tm[6]), tm[7])));
    mx = fmaxf(mx, __shfl_xor(mx, 32, 64));

    // ---- defer-max (T13; THR = 8*log2e in base-2 units)
    if (!__all(mx <= mrow + 11.5416f)) {
      const float mn = fmaxf(mx, mrow);
      const float al = __builtin_amdgcn_exp2f(mrow - mn);
      mrow = mn;
      lsum[0] *= al;
#pragma unroll
      for (int r = 0; r < 16; ++r) { o0[r] *= al; o1[r] *= al; }
    }

    // ---- P = exp2(S' - m)  (no row-sum adds: lsum comes from ones-MFMA)
#pragma unroll
    for (int r = 0; r < 16; ++r) {
      s0[r] = __builtin_amdgcn_exp2f(s0[r] - mrow);
      s1[r] = __builtin_amdgcn_exp2f(s1[r] - mrow);
    }

    // ---- pack P to bf16 words (T12)
    unsigned pk0[8], pk1[8];
#pragma unroll
    for (int ww = 0; ww < 8; ++ww) {
      pk0[ww] = cvtpk(s0[2 * ww], s0[2 * ww + 1]);
      pk1[ww] = cvtpk(s1[2 * ww], s1[2 * ww + 1]);
    }

    // ---- PV (swapped): O^T += V^T · P ; lsum += 1^T · P
    __builtin_amdgcn_s_setprio(1);
#pragma unroll
    for (int c = 0; c < 4; ++c) {
      const int wb = 4 * (c & 1);
      unsigned a0 = (c < 2) ? pk0[wb + 0] : pk1[wb + 0];
      unsigned a1 = (c < 2) ? pk0[wb + 1] : pk1[wb + 1];
      unsigned b0 = (c < 2) ? pk0[wb + 2] : pk1[wb + 2];
      unsigned b1 = (c < 2) ? pk0[wb + 3] : pk1[wb + 3];
      plswap(a0, b0);
      plswap(a1, b1);
      uint32x4 fw = {a0, a1, b0, b1};
      const bf16x8 pf = __builtin_bit_cast(bf16x8, fw);
      const int sl = ((2 * c + hi) ^ swz) * 8;
      o0 = mfma32(ld8(Vs[cur] + q5 * 64 + sl), pf, o0);
      o1 = mfma32(ld8(Vs[cur] + (32 + q5) * 64 + sl), pf, o1);
      lsum = mfma32(onesb, pf, lsum);
    }
    __builtin_amdgcn_s_setprio(0);

    __syncthreads();
  }

  // ---- epilogue: lsum[0] is the full row-sum for q-row q5 (all kv, both hi)
  const float inv = 1.f / lsum[0];
  const int bb = bh >> 4, h = bh & 15;
  unsigned short* Ob = jb.O + ((size_t)bb * SEQ + qrow) * DM + h * HDIM;

  auto storeO = [&](const f32x16 oo, int dbase) {
#pragma unroll
    for (int g4 = 0; g4 < 4; ++g4) {
      ushort4 pv;
      pv.x = f2bf(oo[4 * g4 + 0] * inv);
      pv.y = f2bf(oo[4 * g4 + 1] * inv);
      pv.z = f2bf(oo[4 * g4 + 2] * inv);
      pv.w = f2bf(oo[4 * g4 + 3] * inv);
      *(ushort4*)(Ob + dbase + 8 * g4 + 4 * hi) = pv;  // d = dbase+8*g4+4*hi+i
    }
  };
  storeO(o0, 0);
  storeO(o1, 32);
}

// ---------------------------------------------------------------- launch
extern "C" void kernel_launch(void* const* d_in, const int* in_sizes, int n_in,
                              void* d_out, int out_size, void* d_ws, size_t ws_size,
                              hipStream_t stream) {
  const float* vis = (const float*)d_in[0];
  const float* inff = (const float*)d_in[1];

  unsigned short* xbf  = (unsigned short*)d_ws;        // [2][4096][1024] bf16
  unsigned short* wt   = xbf + 2 * XSZ;                // 8 x [1024][1024] bf16 (transposed)
  unsigned short* Qv   = wt + (size_t)8 * 1024 * 1024; // each [B*H, S, HD]
  unsigned short* Kv   = Qv + XSZ;
  unsigned short* Vv   = Kv + XSZ;                     // (unused)
  unsigned short* Qi   = Vv + XSZ;
  unsigned short* Ki   = Qi + XSZ;
  unsigned short* Vi   = Ki + XSZ;                     // (unused)
  unsigned short* Vvt  = Vi + XSZ;                     // [B*H, HD, S] written by GEMM mode2
  unsigned short* Vit  = Vvt + XSZ;
  unsigned short* atA  = Vit + XSZ;                    // softmax(Qv Ki^T) Vi, [B,S,D]
  unsigned short* atB  = atA + XSZ;                    // softmax(Qi Kv^T) Vv

  k_convert_x<<<dim3(2048, 1, 2), 256, 0, stream>>>(vis, inff, xbf);

  WPtrs wp;
  wp.w[0] = (const float*)d_in[2];  wp.w[1] = (const float*)d_in[4];
  wp.w[2] = (const float*)d_in[6];  wp.w[3] = (const float*)d_in[8];
  wp.w[4] = (const float*)d_in[10]; wp.w[5] = (const float*)d_in[12];
  wp.w[6] = (const float*)d_in[14]; wp.w[7] = (const float*)d_in[16];
  k_convert_w<<<dim3(16, 16, 8), 256, 0, stream>>>(wp, wt);

  const size_t WSZ = (size_t)1024 * 1024;
  const float qsc = 0.18033688011f;  // log2(e)/8 -> softmax in base-2 domain
  GemmJobs pj;
  pj.j[0] = { xbf,       wt + 0 * WSZ, (const float*)d_in[3],  (void*)Qv,  qsc, 0 };
  pj.j[1] = { xbf,       wt + 1 * WSZ, (const float*)d_in[5],  (void*)Kv,  1.f, 0 };
  pj.j[2] = { xbf,       wt + 2 * WSZ, (const float*)d_in[7],  (void*)Vvt, 1.f, 2 };
  pj.j[3] = { xbf + XSZ, wt + 3 * WSZ, (const float*)d_in[9],  (void*)Qi,  qsc, 0 };
  pj.j[4] = { xbf + XSZ, wt + 4 * WSZ, (const float*)d_in[11], (void*)Ki,  1.f, 0 };
  pj.j[5] = { xbf + XSZ, wt + 5 * WSZ, (const float*)d_in[13], (void*)Vit, 1.f, 2 };
  k_gemm<<<dim3(8, 32, 6), 256, 0, stream>>>(pj);

  AttnJobs aj;
  aj.j[0] = { Qv, Ki, Vit, atA };  // vis queries over inf K/V -> out_inf path
  aj.j[1] = { Qi, Kv, Vvt, atB };  // inf queries over vis K/V -> out_vis path
  k_attn<<<dim3(16, 32, 2), 256, 0, stream>>>(aj);

  GemmJobs oj;
  oj.j[0] = { atB, wt + 6 * WSZ, (const float*)d_in[15], d_out, 1.f, 1 };                      // out_vis
  oj.j[1] = { atA, wt + 7 * WSZ, (const float*)d_in[17], (void*)((float*)d_out + XSZ), 1.f, 1 }; // out_inf
  for (int z = 2; z < 6; ++z) oj.j[z] = oj.j[0];  // unused slots
  k_gemm<<<dim3(8, 32, 2), 256, 0, stream>>>(oj);
}

// Round 4
// 313.786 us; speedup vs baseline: 2.1956x; 1.0349x over previous
//
#include <hip/hip_runtime.h>
#include <hip/hip_bf16.h>

#define DEV __device__ __forceinline__

typedef __attribute__((ext_vector_type(4))) float f32x4;
typedef __attribute__((ext_vector_type(16))) float f32x16;
typedef __attribute__((ext_vector_type(8))) __bf16 bf16x8;
typedef __attribute__((ext_vector_type(8))) unsigned short ushort8;
typedef __attribute__((ext_vector_type(4))) unsigned int uint32x4;

static constexpr int BATCH = 2, SEQ = 2048, DM = 1024, NH = 16, HDIM = 64;
static constexpr size_t XSZ = (size_t)BATCH * SEQ * DM;  // 4194304 elems per [4096,1024]

DEV unsigned short f2bf(float f) {
  union { float f; unsigned int u; } v; v.f = f;
  unsigned int r = (v.u + 0x7fffu + ((v.u >> 16) & 1u)) >> 16;  // RNE; inputs are finite
  return (unsigned short)r;
}

DEV bf16x8 ld8(const unsigned short* p) {
  return __builtin_bit_cast(bf16x8, *(const ushort8*)p);
}

DEV f32x4 mfma16(bf16x8 a, bf16x8 b, f32x4 c) {
  return __builtin_amdgcn_mfma_f32_16x16x32_bf16(a, b, c, 0, 0, 0);
}
DEV f32x16 mfma32(bf16x8 a, bf16x8 b, f32x16 c) {
  return __builtin_amdgcn_mfma_f32_32x32x16_bf16(a, b, c, 0, 0, 0);
}

DEV unsigned cvtpk(float lo, float hi) {  // D[15:0]=bf16(lo), D[31:16]=bf16(hi)
  unsigned r;
  asm("v_cvt_pk_bf16_f32 %0, %1, %2" : "=v"(r) : "v"(lo), "v"(hi));
  return r;
}
DEV void plswap(unsigned& a, unsigned& b) {  // swap a.hi-lanes <-> b.lo-lanes
  asm("v_permlane32_swap_b32 %0, %1" : "+v"(a), "+v"(b));
}

// async global->LDS, 16B per lane; lds dest is wave-uniform base + lane*16
DEV void gll16(const unsigned short* g, unsigned short* l) {
  __builtin_amdgcn_global_load_lds(
      (__attribute__((address_space(1))) void*)(unsigned short*)g,
      (__attribute__((address_space(3))) void*)l, 16, 0, 0);
}

// ---------------------------------------------------------------- converts
__global__ __launch_bounds__(256)
void k_convert_x(const float* __restrict__ vis, const float* __restrict__ inff,
                 unsigned short* __restrict__ out) {
  const float* src = blockIdx.z ? inff : vis;
  unsigned short* dst = out + (size_t)blockIdx.z * XSZ;
  const size_t i = ((size_t)blockIdx.x * 256 + threadIdx.x) * 8;
  const float4 a = *(const float4*)(src + i);
  const float4 b = *(const float4*)(src + i + 4);
  ushort8 v;
  v[0] = f2bf(a.x); v[1] = f2bf(a.y); v[2] = f2bf(a.z); v[3] = f2bf(a.w);
  v[4] = f2bf(b.x); v[5] = f2bf(b.y); v[6] = f2bf(b.z); v[7] = f2bf(b.w);
  *(ushort8*)(dst + i) = v;
}

struct WPtrs { const float* w[8]; };

// W fp32 [K=1024][N=1024] row-major  ->  Wt bf16 [N][K] row-major
__global__ __launch_bounds__(256)
void k_convert_w(WPtrs p, unsigned short* __restrict__ wt) {
  const float* W = p.w[blockIdx.z];
  unsigned short* Wt = wt + (size_t)blockIdx.z * (1024 * 1024);
  const int k0 = blockIdx.y * 64, n0 = blockIdx.x * 64;
  __shared__ unsigned short t[64][68];
  const int tx = threadIdx.x & 15, ty = threadIdx.x >> 4;
#pragma unroll
  for (int i = 0; i < 4; ++i) {
    const int kr = ty * 4 + i;
    const float4 v = *(const float4*)(W + (size_t)(k0 + kr) * 1024 + n0 + tx * 4);
    t[kr][tx * 4 + 0] = f2bf(v.x); t[kr][tx * 4 + 1] = f2bf(v.y);
    t[kr][tx * 4 + 2] = f2bf(v.z); t[kr][tx * 4 + 3] = f2bf(v.w);
  }
  __syncthreads();
#pragma unroll
  for (int i = 0; i < 4; ++i) {
    const int nr = ty * 4 + i;
    ushort4 o;
    o.x = t[tx * 4 + 0][nr]; o.y = t[tx * 4 + 1][nr];
    o.z = t[tx * 4 + 2][nr]; o.w = t[tx * 4 + 3][nr];
    *(ushort4*)(Wt + (size_t)(n0 + nr) * 1024 + k0 + tx * 4) = o;
  }
}

// ---------------------------------------------------------------- GEMM
// C[4096,1024] = A[4096,1024](bf16) @ Wt[1024(n),1024(k)]^T(bf16) + bias
// mode 0: bf16 heads [B,H,S,HD] (value * scale)   (Q, K)
// mode 2: bf16 heads transposed [B,H,HD,S]        (V)
// mode 1: fp32 row-major [4096,1024]              (O-proj)
struct GemmJob { const unsigned short* A; const unsigned short* W;
                 const float* bias; void* out; float scale; int mode; };
struct GemmJobs { GemmJob j[6]; };

__global__ __launch_bounds__(256)
void k_gemm(GemmJobs jobs) {
  const GemmJob jb = jobs.j[blockIdx.z];
  const int lane = threadIdx.x & 63, w = threadIdx.x >> 6;
  const int wr = w >> 1, wc = w & 1;               // 2x2 wave grid, 64x64 each
  const int r = lane & 15, g = lane >> 4;

  // XCD-chunked bijective swizzle (grid x=8, y=32): each XCD owns 4 contiguous
  // m-tiles (A-panel reuse in its private L2).
  const int nid = blockIdx.x + (blockIdx.y << 3);        // 0..255
  const int bxs = nid >> 5;                              // n-tile 0..7
  const int bys = ((nid & 7) << 2) + ((nid >> 3) & 3);   // m-tile 0..31
  const int bm = bys * 128, bn = bxs * 128;

  __shared__ __align__(16) unsigned short As[128 * 64];  // [row][k] swizzled
  __shared__ __align__(16) unsigned short Bs[128 * 64];

  const int srow = lane >> 3;
  const int schunk = (lane & 7) ^ srow;
  const unsigned short* Ag = jb.A + (size_t)(bm + w * 32 + srow) * DM + schunk * 8;
  const unsigned short* Bg = jb.W + (size_t)(bn + w * 32 + srow) * DM + schunk * 8;

  f32x4 acc[4][4] = {};

  for (int kt = 0; kt < DM; kt += 64) {
#pragma unroll
    for (int j = 0; j < 4; ++j) {
      gll16(Ag + kt + j * 8 * DM, As + (w * 4 + j) * 512);
      gll16(Bg + kt + j * 8 * DM, Bs + (w * 4 + j) * 512);
    }
    __syncthreads();
#pragma unroll
    for (int kk = 0; kk < 2; ++kk) {
      bf16x8 a[4], b[4];
#pragma unroll
      for (int m = 0; m < 4; ++m) {
        const int row = wr * 64 + m * 16 + r;
        const int pos = (kk * 4 + g) ^ (row & 7);
        a[m] = ld8(As + row * 64 + pos * 8);
      }
#pragma unroll
      for (int n = 0; n < 4; ++n) {
        const int row = wc * 64 + n * 16 + r;
        const int pos = (kk * 4 + g) ^ (row & 7);
        b[n] = ld8(Bs + row * 64 + pos * 8);
      }
#pragma unroll
      for (int m = 0; m < 4; ++m)
#pragma unroll
        for (int n = 0; n < 4; ++n)
          acc[m][n] = mfma16(a[m], b[n], acc[m][n]);
    }
    __syncthreads();
  }

  // epilogue; C/D frag: row = 4*g + i, col = r (m89-verified)
  if (jb.mode == 0) {
    unsigned short* O = (unsigned short*)jb.out;
#pragma unroll
    for (int n = 0; n < 4; ++n) {
      const int nc = bn + wc * 64 + n * 16 + r;
      const float bv = jb.bias[nc];
      const int h = nc >> 6, hd = nc & 63;
#pragma unroll
      for (int m = 0; m < 4; ++m)
#pragma unroll
        for (int i = 0; i < 4; ++i) {
          const int mr = bm + wr * 64 + m * 16 + g * 4 + i;
          const int bb = mr >> 11, s = mr & 2047;
          O[((size_t)(bb * NH + h) * SEQ + s) * HDIM + hd] =
              f2bf((acc[m][n][i] + bv) * jb.scale);
        }
    }
  } else if (jb.mode == 2) {
    unsigned short* O = (unsigned short*)jb.out;
#pragma unroll
    for (int n = 0; n < 4; ++n) {
      const int nc = bn + wc * 64 + n * 16 + r;
      const float bv = jb.bias[nc];
      const int h = nc >> 6, hd = nc & 63;
#pragma unroll
      for (int m = 0; m < 4; ++m) {
        const int mr = bm + wr * 64 + m * 16 + g * 4;   // quad-aligned s
        const int bb = mr >> 11, s = mr & 2047;
        ushort4 pv;
        pv.x = f2bf(acc[m][n][0] + bv);
        pv.y = f2bf(acc[m][n][1] + bv);
        pv.z = f2bf(acc[m][n][2] + bv);
        pv.w = f2bf(acc[m][n][3] + bv);
        *(ushort4*)(O + ((size_t)(bb * NH + h) * HDIM + hd) * SEQ + s) = pv;
      }
    }
  } else {
    float* O = (float*)jb.out;
#pragma unroll
    for (int n = 0; n < 4; ++n) {
      const int nc = bn + wc * 64 + n * 16 + r;
      const float bv = jb.bias[nc];
#pragma unroll
      for (int m = 0; m < 4; ++m)
#pragma unroll
        for (int i = 0; i < 4; ++i) {
          const int mr = bm + wr * 64 + m * 16 + g * 4 + i;
          O[(size_t)mr * DM + nc] = acc[m][n][i] + bv;
        }
    }
  }
}

// ---------------------------------------------------------------- attention
// 4 waves/block, 32 q-rows/wave, KVBLK=64, swapped QK^T and PV (32x32x16 MFMA).
// S' = S*log2e (log2e/8 folded into Q projection): softmax is native exp2.
// Row-sum l via ones-MFMA. TRIPLE-buffered K/V staging with counted vmcnt
// (T3+T4): stage tile t+2 at iter t; end-of-iter s_waitcnt vmcnt(4) + raw
// s_barrier keeps t+2's 4 loads in flight across the barrier (never drain 0).
struct AttnJob { const unsigned short* Q; const unsigned short* K;
                 const unsigned short* Vt; unsigned short* O; };
struct AttnJobs { AttnJob j[2]; };

__global__ __launch_bounds__(256)
void k_attn(AttnJobs jobs) {
  const AttnJob jb = jobs.j[blockIdx.z];
  // XCD-chunked swizzle (grid x=16, y=32): each XCD owns 4 contiguous bh
  // so its private L2 holds just those K/V panels.
  const int nid = blockIdx.x + (blockIdx.y << 4);        // 0..511
  const int bx = nid >> 5;                               // q-tile 0..15
  const int bh = ((nid & 7) << 2) + ((nid >> 3) & 3);    // bh 0..31
  const int lane = threadIdx.x & 63, w = threadIdx.x >> 6;
  const int q5 = lane & 31, hi = lane >> 5;
  const int qrow = bx * 128 + w * 32 + q5;

  const unsigned short* Qp = jb.Q + (size_t)bh * SEQ * HDIM;
  const unsigned short* Kp = jb.K + (size_t)bh * SEQ * HDIM;
  const unsigned short* Vp = jb.Vt + (size_t)bh * HDIM * SEQ;

  __shared__ __align__(16) unsigned short Ks[3][64 * 64];
  __shared__ __align__(16) unsigned short Vs[3][64 * 64];

  // Q fragments (B-operand): qf[c] = Q[qrow][c*16 + hi*8 .. +7]
  bf16x8 qf[4];
#pragma unroll
  for (int c = 0; c < 4; ++c)
    qf[c] = ld8(Qp + (size_t)qrow * HDIM + c * 16 + hi * 8);

  // ones A-fragment for the row-sum MFMA (value layout-independent)
  ushort8 ov;
#pragma unroll
  for (int i = 0; i < 8; ++i) ov[i] = 0x3f80;  // bf16 1.0
  const bf16x8 onesb = __builtin_bit_cast(bf16x8, ov);

  const int srow = lane >> 3;
  const int sslot = lane & 7;

  auto stage = [&](int buf, int kv0) {
#pragma unroll
    for (int j = 0; j < 2; ++j) {
      const int row = j * 32 + w * 8 + srow;          // 0..63
      const int u = sslot ^ (row & 7);
      gll16(Kp + (size_t)(kv0 + row) * HDIM + u * 8, Ks[buf] + (j * 32 + w * 8) * 64);
      gll16(Vp + (size_t)row * SEQ + kv0 + u * 8,    Vs[buf] + (j * 32 + w * 8) * 64);
    }
  };

  f32x16 o0 = {}, o1 = {}, lsum = {};
  float mrow = -1e30f;
  const int swz = q5 & 7;
  constexpr int NT = SEQ / 64;  // 32

  // prologue: fill buffers 0 and 1; wait only for buffer 0 (vmcnt(4))
  stage(0, 0);
  stage(1, 64);
  asm volatile("s_waitcnt vmcnt(4)" ::: "memory");
  __builtin_amdgcn_s_barrier();
  __builtin_amdgcn_sched_barrier(0);

  int cur = 0, sb = 2;
  for (int t = 0; t < NT; ++t) {
    if (t + 2 < NT) stage(sb, (t + 2) * 64);

    // ---- QK^T (swapped): S'^T[kv][q], two 32-kv tiles
    f32x16 s0 = {}, s1 = {};
    __builtin_amdgcn_s_setprio(1);
#pragma unroll
    for (int c = 0; c < 4; ++c) {
      const int sl = ((2 * c + hi) ^ swz) * 8;
      s0 = mfma32(ld8(Ks[cur] + q5 * 64 + sl), qf[c], s0);
      s1 = mfma32(ld8(Ks[cur] + (32 + q5) * 64 + sl), qf[c], s1);
    }
    __builtin_amdgcn_s_setprio(0);

    // ---- row max (in-register tree + 1 partner exchange)
    float tm[8];
#pragma unroll
    for (int r = 0; r < 8; ++r)
      tm[r] = fmaxf(fmaxf(s0[r], s0[r + 8]), fmaxf(s1[r], s1[r + 8]));
    float mx = fmaxf(fmaxf(fmaxf(tm[0], tm[1]), tm[2]),
                     fmaxf(fmaxf(tm[3], tm[4]), fmaxf(fmaxf(tm[5], tm[6]), tm[7])));
    mx = fmaxf(mx, __shfl_xor(mx, 32, 64));

    // ---- defer-max (T13; THR = 8*log2e in base-2 units)
    if (!__all(mx <= mrow + 11.5416f)) {
      const float mn = fmaxf(mx, mrow);
      const float al = __builtin_amdgcn_exp2f(mrow - mn);
      mrow = mn;
      lsum[0] *= al;
#pragma unroll
      for (int r = 0; r < 16; ++r) { o0[r] *= al; o1[r] *= al; }
    }

    // ---- P = exp2(S' - m)
#pragma unroll
    for (int r = 0; r < 16; ++r) {
      s0[r] = __builtin_amdgcn_exp2f(s0[r] - mrow);
      s1[r] = __builtin_amdgcn_exp2f(s1[r] - mrow);
    }

    // ---- pack P to bf16 words (T12)
    unsigned pk0[8], pk1[8];
#pragma unroll
    for (int ww = 0; ww < 8; ++ww) {
      pk0[ww] = cvtpk(s0[2 * ww], s0[2 * ww + 1]);
      pk1[ww] = cvtpk(s1[2 * ww], s1[2 * ww + 1]);
    }

    // ---- PV (swapped): O^T += V^T · P ; lsum += 1^T · P
    __builtin_amdgcn_s_setprio(1);
#pragma unroll
    for (int c = 0; c < 4; ++c) {
      const int wb = 4 * (c & 1);
      unsigned a0 = (c < 2) ? pk0[wb + 0] : pk1[wb + 0];
      unsigned a1 = (c < 2) ? pk0[wb + 1] : pk1[wb + 1];
      unsigned b0 = (c < 2) ? pk0[wb + 2] : pk1[wb + 2];
      unsigned b1 = (c < 2) ? pk0[wb + 3] : pk1[wb + 3];
      plswap(a0, b0);
      plswap(a1, b1);
      uint32x4 fw = {a0, a1, b0, b1};
      const bf16x8 pf = __builtin_bit_cast(bf16x8, fw);
      const int sl = ((2 * c + hi) ^ swz) * 8;
      o0 = mfma32(ld8(Vs[cur] + q5 * 64 + sl), pf, o0);
      o1 = mfma32(ld8(Vs[cur] + (32 + q5) * 64 + sl), pf, o1);
      lsum = mfma32(onesb, pf, lsum);
    }
    __builtin_amdgcn_s_setprio(0);

    // ---- counted-vmcnt barrier (T4): keep t+2's 4 loads in flight.
    // At end of t: outstanding = (t+1)'s 4 + (t+2)'s 4 -> wait 4 drains t+1.
    if (t + 1 < NT) {
      if (t + 2 < NT) {
        asm volatile("s_waitcnt vmcnt(4)" ::: "memory");
      } else {
        asm volatile("s_waitcnt vmcnt(0)" ::: "memory");
      }
      __builtin_amdgcn_s_barrier();
      __builtin_amdgcn_sched_barrier(0);
    }
    sb = cur;
    cur = (cur == 2) ? 0 : cur + 1;
  }

  // ---- epilogue: lsum[0] is the full row-sum for q-row q5 (all kv, both hi)
  const float inv = 1.f / lsum[0];
  const int bb = bh >> 4, h = bh & 15;
  unsigned short* Ob = jb.O + ((size_t)bb * SEQ + qrow) * DM + h * HDIM;

  auto storeO = [&](const f32x16 oo, int dbase) {
#pragma unroll
    for (int g4 = 0; g4 < 4; ++g4) {
      ushort4 pv;
      pv.x = f2bf(oo[4 * g4 + 0] * inv);
      pv.y = f2bf(oo[4 * g4 + 1] * inv);
      pv.z = f2bf(oo[4 * g4 + 2] * inv);
      pv.w = f2bf(oo[4 * g4 + 3] * inv);
      *(ushort4*)(Ob + dbase + 8 * g4 + 4 * hi) = pv;  // d = dbase+8*g4+4*hi+i
    }
  };
  storeO(o0, 0);
  storeO(o1, 32);
}

// ---------------------------------------------------------------- launch
extern "C" void kernel_launch(void* const* d_in, const int* in_sizes, int n_in,
                              void* d_out, int out_size, void* d_ws, size_t ws_size,
                              hipStream_t stream) {
  const float* vis = (const float*)d_in[0];
  const float* inff = (const float*)d_in[1];

  unsigned short* xbf  = (unsigned short*)d_ws;        // [2][4096][1024] bf16
  unsigned short* wt   = xbf + 2 * XSZ;                // 8 x [1024][1024] bf16 (transposed)
  unsigned short* Qv   = wt + (size_t)8 * 1024 * 1024; // each [B*H, S, HD]
  unsigned short* Kv   = Qv + XSZ;
  unsigned short* Vv   = Kv + XSZ;                     // (unused)
  unsigned short* Qi   = Vv + XSZ;
  unsigned short* Ki   = Qi + XSZ;
  unsigned short* Vi   = Ki + XSZ;                     // (unused)
  unsigned short* Vvt  = Vi + XSZ;                     // [B*H, HD, S] written by GEMM mode2
  unsigned short* Vit  = Vvt + XSZ;
  unsigned short* atA  = Vit + XSZ;                    // softmax(Qv Ki^T) Vi, [B,S,D]
  unsigned short* atB  = atA + XSZ;                    // softmax(Qi Kv^T) Vv

  k_convert_x<<<dim3(2048, 1, 2), 256, 0, stream>>>(vis, inff, xbf);

  WPtrs wp;
  wp.w[0] = (const float*)d_in[2];  wp.w[1] = (const float*)d_in[4];
  wp.w[2] = (const float*)d_in[6];  wp.w[3] = (const float*)d_in[8];
  wp.w[4] = (const float*)d_in[10]; wp.w[5] = (const float*)d_in[12];
  wp.w[6] = (const float*)d_in[14]; wp.w[7] = (const float*)d_in[16];
  k_convert_w<<<dim3(16, 16, 8), 256, 0, stream>>>(wp, wt);

  const size_t WSZ = (size_t)1024 * 1024;
  const float qsc = 0.18033688011f;  // log2(e)/8 -> softmax in base-2 domain
  GemmJobs pj;
  pj.j[0] = { xbf,       wt + 0 * WSZ, (const float*)d_in[3],  (void*)Qv,  qsc, 0 };
  pj.j[1] = { xbf,       wt + 1 * WSZ, (const float*)d_in[5],  (void*)Kv,  1.f, 0 };
  pj.j[2] = { xbf,       wt + 2 * WSZ, (const float*)d_in[7],  (void*)Vvt, 1.f, 2 };
  pj.j[3] = { xbf + XSZ, wt + 3 * WSZ, (const float*)d_in[9],  (void*)Qi,  qsc, 0 };
  pj.j[4] = { xbf + XSZ, wt + 4 * WSZ, (const float*)d_in[11], (void*)Ki,  1.f, 0 };
  pj.j[5] = { xbf + XSZ, wt + 5 * WSZ, (const float*)d_in[13], (void*)Vit, 1.f, 2 };
  k_gemm<<<dim3(8, 32, 6), 256, 0, stream>>>(pj);

  AttnJobs aj;
  aj.j[0] = { Qv, Ki, Vit, atA };  // vis queries over inf K/V -> out_inf path
  aj.j[1] = { Qi, Kv, Vvt, atB };  // inf queries over vis K/V -> out_vis path
  k_attn<<<dim3(16, 32, 2), 256, 0, stream>>>(aj);

  GemmJobs oj;
  oj.j[0] = { atB, wt + 6 * WSZ, (const float*)d_in[15], d_out, 1.f, 1 };                      // out_vis
  oj.j[1] = { atA, wt + 7 * WSZ, (const float*)d_in[17], (void*)((float*)d_out + XSZ), 1.f, 1 }; // out_inf
  for (int z = 2; z < 6; ++z) oj.j[z] = oj.j[0];  // unused slots
  k_gemm<<<dim3(8, 32, 2), 256, 0, stream>>>(oj);
}

// Round 5
// 303.760 us; speedup vs baseline: 2.2681x; 1.0330x over previous
//
#include <hip/hip_runtime.h>
#include <hip/hip_bf16.h>

#define DEV __device__ __forceinline__

typedef __attribute__((ext_vector_type(4))) float f32x4;
typedef __attribute__((ext_vector_type(16))) float f32x16;
typedef __attribute__((ext_vector_type(8))) __bf16 bf16x8;
typedef __attribute__((ext_vector_type(8))) unsigned short ushort8;
typedef __attribute__((ext_vector_type(4))) unsigned int uint32x4;

static constexpr int BATCH = 2, SEQ = 2048, DM = 1024, NH = 16, HDIM = 64;
static constexpr size_t XSZ = (size_t)BATCH * SEQ * DM;  // 4194304 elems per [4096,1024]

DEV unsigned short f2bf(float f) {
  union { float f; unsigned int u; } v; v.f = f;
  unsigned int r = (v.u + 0x7fffu + ((v.u >> 16) & 1u)) >> 16;  // RNE; inputs are finite
  return (unsigned short)r;
}

DEV bf16x8 ld8(const unsigned short* p) {
  return __builtin_bit_cast(bf16x8, *(const ushort8*)p);
}

DEV f32x4 mfma16(bf16x8 a, bf16x8 b, f32x4 c) {
  return __builtin_amdgcn_mfma_f32_16x16x32_bf16(a, b, c, 0, 0, 0);
}
DEV f32x16 mfma32(bf16x8 a, bf16x8 b, f32x16 c) {
  return __builtin_amdgcn_mfma_f32_32x32x16_bf16(a, b, c, 0, 0, 0);
}

DEV unsigned cvtpk(float lo, float hi) {  // D[15:0]=bf16(lo), D[31:16]=bf16(hi)
  unsigned r;
  asm("v_cvt_pk_bf16_f32 %0, %1, %2" : "=v"(r) : "v"(lo), "v"(hi));
  return r;
}
DEV void plswap(unsigned& a, unsigned& b) {  // swap a.hi-lanes <-> b.lo-lanes
  asm("v_permlane32_swap_b32 %0, %1" : "+v"(a), "+v"(b));
}

// async global->LDS, 16B per lane; lds dest is wave-uniform base + lane*16
DEV void gll16(const unsigned short* g, unsigned short* l) {
  __builtin_amdgcn_global_load_lds(
      (__attribute__((address_space(1))) void*)(unsigned short*)g,
      (__attribute__((address_space(3))) void*)l, 16, 0, 0);
}

// ---------------------------------------------------------------- converts
__global__ __launch_bounds__(256)
void k_convert_x(const float* __restrict__ vis, const float* __restrict__ inff,
                 unsigned short* __restrict__ out) {
  const float* src = blockIdx.z ? inff : vis;
  unsigned short* dst = out + (size_t)blockIdx.z * XSZ;
  const size_t i = ((size_t)blockIdx.x * 256 + threadIdx.x) * 8;
  const float4 a = *(const float4*)(src + i);
  const float4 b = *(const float4*)(src + i + 4);
  ushort8 v;
  v[0] = f2bf(a.x); v[1] = f2bf(a.y); v[2] = f2bf(a.z); v[3] = f2bf(a.w);
  v[4] = f2bf(b.x); v[5] = f2bf(b.y); v[6] = f2bf(b.z); v[7] = f2bf(b.w);
  *(ushort8*)(dst + i) = v;
}

struct WPtrs { const float* w[8]; };

// W fp32 [K=1024][N=1024] row-major  ->  Wt bf16 [N][K] row-major
__global__ __launch_bounds__(256)
void k_convert_w(WPtrs p, unsigned short* __restrict__ wt) {
  const float* W = p.w[blockIdx.z];
  unsigned short* Wt = wt + (size_t)blockIdx.z * (1024 * 1024);
  const int k0 = blockIdx.y * 64, n0 = blockIdx.x * 64;
  __shared__ unsigned short t[64][68];
  const int tx = threadIdx.x & 15, ty = threadIdx.x >> 4;
#pragma unroll
  for (int i = 0; i < 4; ++i) {
    const int kr = ty * 4 + i;
    const float4 v = *(const float4*)(W + (size_t)(k0 + kr) * 1024 + n0 + tx * 4);
    t[kr][tx * 4 + 0] = f2bf(v.x); t[kr][tx * 4 + 1] = f2bf(v.y);
    t[kr][tx * 4 + 2] = f2bf(v.z); t[kr][tx * 4 + 3] = f2bf(v.w);
  }
  __syncthreads();
#pragma unroll
  for (int i = 0; i < 4; ++i) {
    const int nr = ty * 4 + i;
    ushort4 o;
    o.x = t[tx * 4 + 0][nr]; o.y = t[tx * 4 + 1][nr];
    o.z = t[tx * 4 + 2][nr]; o.w = t[tx * 4 + 3][nr];
    *(ushort4*)(Wt + (size_t)(n0 + nr) * 1024 + k0 + tx * 4) = o;
  }
}

// ---------------------------------------------------------------- GEMM
// C[4096,1024] = A[4096,1024](bf16) @ Wt[1024(n),1024(k)]^T(bf16) + bias
// mode 0: bf16 heads [B,H,S,HD] (value * scale)   (Q, K)
// mode 2: bf16 heads transposed [B,H,HD,S]        (V)
// mode 1: fp32 row-major [4096,1024]              (O-proj)
struct GemmJob { const unsigned short* A; const unsigned short* W;
                 const float* bias; void* out; float scale; int mode; };
struct GemmJobs { GemmJob j[6]; };

__global__ __launch_bounds__(256)
void k_gemm(GemmJobs jobs) {
  const GemmJob jb = jobs.j[blockIdx.z];
  const int lane = threadIdx.x & 63, w = threadIdx.x >> 6;
  const int wr = w >> 1, wc = w & 1;               // 2x2 wave grid, 64x64 each
  const int r = lane & 15, g = lane >> 4;

  // XCD-chunked bijective swizzle (grid x=8, y=32): each XCD owns 4 contiguous
  // m-tiles (A-panel reuse in its private L2).
  const int nid = blockIdx.x + (blockIdx.y << 3);        // 0..255
  const int bxs = nid >> 5;                              // n-tile 0..7
  const int bys = ((nid & 7) << 2) + ((nid >> 3) & 3);   // m-tile 0..31
  const int bm = bys * 128, bn = bxs * 128;

  __shared__ __align__(16) unsigned short As[128 * 64];  // [row][k] swizzled
  __shared__ __align__(16) unsigned short Bs[128 * 64];

  const int srow = lane >> 3;
  const int schunk = (lane & 7) ^ srow;
  const unsigned short* Ag = jb.A + (size_t)(bm + w * 32 + srow) * DM + schunk * 8;
  const unsigned short* Bg = jb.W + (size_t)(bn + w * 32 + srow) * DM + schunk * 8;

  f32x4 acc[4][4] = {};

  for (int kt = 0; kt < DM; kt += 64) {
#pragma unroll
    for (int j = 0; j < 4; ++j) {
      gll16(Ag + kt + j * 8 * DM, As + (w * 4 + j) * 512);
      gll16(Bg + kt + j * 8 * DM, Bs + (w * 4 + j) * 512);
    }
    __syncthreads();
#pragma unroll
    for (int kk = 0; kk < 2; ++kk) {
      bf16x8 a[4], b[4];
#pragma unroll
      for (int m = 0; m < 4; ++m) {
        const int row = wr * 64 + m * 16 + r;
        const int pos = (kk * 4 + g) ^ (row & 7);
        a[m] = ld8(As + row * 64 + pos * 8);
      }
#pragma unroll
      for (int n = 0; n < 4; ++n) {
        const int row = wc * 64 + n * 16 + r;
        const int pos = (kk * 4 + g) ^ (row & 7);
        b[n] = ld8(Bs + row * 64 + pos * 8);
      }
#pragma unroll
      for (int m = 0; m < 4; ++m)
#pragma unroll
        for (int n = 0; n < 4; ++n)
          acc[m][n] = mfma16(a[m], b[n], acc[m][n]);
    }
    __syncthreads();
  }

  // epilogue; C/D frag: row = 4*g + i, col = r (m89-verified)
  if (jb.mode == 0) {
    unsigned short* O = (unsigned short*)jb.out;
#pragma unroll
    for (int n = 0; n < 4; ++n) {
      const int nc = bn + wc * 64 + n * 16 + r;
      const float bv = jb.bias[nc];
      const int h = nc >> 6, hd = nc & 63;
#pragma unroll
      for (int m = 0; m < 4; ++m)
#pragma unroll
        for (int i = 0; i < 4; ++i) {
          const int mr = bm + wr * 64 + m * 16 + g * 4 + i;
          const int bb = mr >> 11, s = mr & 2047;
          O[((size_t)(bb * NH + h) * SEQ + s) * HDIM + hd] =
              f2bf((acc[m][n][i] + bv) * jb.scale);
        }
    }
  } else if (jb.mode == 2) {
    unsigned short* O = (unsigned short*)jb.out;
#pragma unroll
    for (int n = 0; n < 4; ++n) {
      const int nc = bn + wc * 64 + n * 16 + r;
      const float bv = jb.bias[nc];
      const int h = nc >> 6, hd = nc & 63;
#pragma unroll
      for (int m = 0; m < 4; ++m) {
        const int mr = bm + wr * 64 + m * 16 + g * 4;   // quad-aligned s
        const int bb = mr >> 11, s = mr & 2047;
        ushort4 pv;
        pv.x = f2bf(acc[m][n][0] + bv);
        pv.y = f2bf(acc[m][n][1] + bv);
        pv.z = f2bf(acc[m][n][2] + bv);
        pv.w = f2bf(acc[m][n][3] + bv);
        *(ushort4*)(O + ((size_t)(bb * NH + h) * HDIM + hd) * SEQ + s) = pv;
      }
    }
  } else {
    float* O = (float*)jb.out;
#pragma unroll
    for (int n = 0; n < 4; ++n) {
      const int nc = bn + wc * 64 + n * 16 + r;
      const float bv = jb.bias[nc];
#pragma unroll
      for (int m = 0; m < 4; ++m)
#pragma unroll
        for (int i = 0; i < 4; ++i) {
          const int mr = bm + wr * 64 + m * 16 + g * 4 + i;
          O[(size_t)mr * DM + nc] = acc[m][n][i] + bv;
        }
    }
  }
}

// ---------------------------------------------------------------- attention
// 8 waves/block (512 thr), 32 q-rows/wave = 256 q-rows/block, KVBLK=64.
// Swapped QK^T and PV (32x32x16). S' in base-2 (log2e/8 folded into Q proj).
// Row-sum via VALU partials + one partner shfl (reg-lean: no lsum AGPRs).
// Triple-buffered K/V staging, counted vmcnt(2) barriers (T3+T4).
// __launch_bounds__(512,4): force total regs <=128 -> 4 waves/SIMD resident.
struct AttnJob { const unsigned short* Q; const unsigned short* K;
                 const unsigned short* Vt; unsigned short* O; };
struct AttnJobs { AttnJob j[2]; };

__global__ __launch_bounds__(512, 4)
void k_attn(AttnJobs jobs) {
  const AttnJob jb = jobs.j[blockIdx.z];
  // XCD-chunked swizzle (grid x=8, y=32): linear id L = x + 8y (+256z), XCD =
  // L&7 -> each XCD owns bh {4a..4a+3} (K/V panels L2-resident).
  const int nid = blockIdx.x + (blockIdx.y << 3);        // 0..255
  const int qt = nid >> 5;                               // q-tile 0..7
  const int bh = ((nid & 7) << 2) + ((nid >> 3) & 3);    // bh 0..31
  const int lane = threadIdx.x & 63, w = threadIdx.x >> 6;  // w 0..7
  const int q5 = lane & 31, hi = lane >> 5;
  const int qrow = qt * 256 + w * 32 + q5;

  const unsigned short* Qp = jb.Q + (size_t)bh * SEQ * HDIM;
  const unsigned short* Kp = jb.K + (size_t)bh * SEQ * HDIM;
  const unsigned short* Vp = jb.Vt + (size_t)bh * HDIM * SEQ;

  __shared__ __align__(16) unsigned short Ks[3][64 * 64];
  __shared__ __align__(16) unsigned short Vs[3][64 * 64];

  // Q fragments (B-operand): qf[c] = Q[qrow][c*16 + hi*8 .. +7]
  bf16x8 qf[4];
#pragma unroll
  for (int c = 0; c < 4; ++c)
    qf[c] = ld8(Qp + (size_t)qrow * HDIM + c * 16 + hi * 8);

  // staging: wave w covers rows w*8..w*8+7 of K (seq rows) and Vt (hd rows);
  // lane -> row w*8 + (l>>3), lds slot l&7, source chunk = slot ^ (row&7).
  const int srow = w * 8 + (lane >> 3);
  const int schunk = (lane & 7) ^ (srow & 7);
  const unsigned short* Kg = Kp + (size_t)srow * HDIM + schunk * 8;
  const unsigned short* Vg = Vp + (size_t)srow * SEQ + schunk * 8;

  auto stage = [&](int buf, int kv0) {
    gll16(Kg + (size_t)kv0 * HDIM, Ks[buf] + w * 512);
    gll16(Vg + kv0,                Vs[buf] + w * 512);
  };

  f32x16 o0 = {}, o1 = {};
  float mrow = -1e30f, lrow = 0.f;
  const int swz = q5 & 7;
  constexpr int NT = SEQ / 64;  // 32

  // prologue: fill buffers 0 and 1; wait only for buffer 0 (vmcnt(2))
  stage(0, 0);
  stage(1, 64);
  asm volatile("s_waitcnt vmcnt(2)" ::: "memory");
  __builtin_amdgcn_s_barrier();
  __builtin_amdgcn_sched_barrier(0);

  int cur = 0, sb = 2;
  for (int t = 0; t < NT; ++t) {
    if (t + 2 < NT) stage(sb, (t + 2) * 64);

    // ---- QK^T (swapped): S'^T[kv][q], two 32-kv tiles
    f32x16 s0 = {}, s1 = {};
    __builtin_amdgcn_s_setprio(1);
#pragma unroll
    for (int c = 0; c < 4; ++c) {
      const int sl = ((2 * c + hi) ^ swz) * 8;
      s0 = mfma32(ld8(Ks[cur] + q5 * 64 + sl), qf[c], s0);
      s1 = mfma32(ld8(Ks[cur] + (32 + q5) * 64 + sl), qf[c], s1);
    }
    __builtin_amdgcn_s_setprio(0);

    // ---- row max (in-register tree + 1 partner exchange)
    float tm[8];
#pragma unroll
    for (int r = 0; r < 8; ++r)
      tm[r] = fmaxf(fmaxf(s0[r], s0[r + 8]), fmaxf(s1[r], s1[r + 8]));
    float mx = fmaxf(fmaxf(fmaxf(tm[0], tm[1]), tm[2]),
                     fmaxf(fmaxf(tm[3], tm[4]), fmaxf(fmaxf(tm[5], tm[6]), tm[7])));
    mx = fmaxf(mx, __shfl_xor(mx, 32, 64));

    // ---- defer-max (T13; THR = 8*log2e in base-2 units)
    if (!__all(mx <= mrow + 11.5416f)) {
      const float mn = fmaxf(mx, mrow);
      const float al = __builtin_amdgcn_exp2f(mrow - mn);
      mrow = mn;
      lrow *= al;
#pragma unroll
      for (int r = 0; r < 16; ++r) { o0[r] *= al; o1[r] *= al; }
    }

    // ---- P = exp2(S' - m) + partial row-sum (own 32 kv; partner has rest)
    float ps0 = 0.f, ps1 = 0.f;
#pragma unroll
    for (int r = 0; r < 16; ++r) {
      s0[r] = __builtin_amdgcn_exp2f(s0[r] - mrow); ps0 += s0[r];
      s1[r] = __builtin_amdgcn_exp2f(s1[r] - mrow); ps1 += s1[r];
    }
    lrow += ps0 + ps1;

    // ---- pack P to bf16 words (T12)
    unsigned pk0[8], pk1[8];
#pragma unroll
    for (int ww = 0; ww < 8; ++ww) {
      pk0[ww] = cvtpk(s0[2 * ww], s0[2 * ww + 1]);
      pk1[ww] = cvtpk(s1[2 * ww], s1[2 * ww + 1]);
    }

    // ---- PV (swapped): O^T += V^T · P
    __builtin_amdgcn_s_setprio(1);
#pragma unroll
    for (int c = 0; c < 4; ++c) {
      const int wb = 4 * (c & 1);
      unsigned a0 = (c < 2) ? pk0[wb + 0] : pk1[wb + 0];
      unsigned a1 = (c < 2) ? pk0[wb + 1] : pk1[wb + 1];
      unsigned b0 = (c < 2) ? pk0[wb + 2] : pk1[wb + 2];
      unsigned b1 = (c < 2) ? pk0[wb + 3] : pk1[wb + 3];
      plswap(a0, b0);
      plswap(a1, b1);
      uint32x4 fw = {a0, a1, b0, b1};
      const bf16x8 pf = __builtin_bit_cast(bf16x8, fw);
      const int sl = ((2 * c + hi) ^ swz) * 8;
      o0 = mfma32(ld8(Vs[cur] + q5 * 64 + sl), pf, o0);
      o1 = mfma32(ld8(Vs[cur] + (32 + q5) * 64 + sl), pf, o1);
    }
    __builtin_amdgcn_s_setprio(0);

    // ---- counted-vmcnt barrier (T4): keep t+2's 2 loads in flight.
    if (t + 1 < NT) {
      if (t + 2 < NT) {
        asm volatile("s_waitcnt vmcnt(2)" ::: "memory");
      } else {
        asm volatile("s_waitcnt vmcnt(0)" ::: "memory");
      }
      __builtin_amdgcn_s_barrier();
      __builtin_amdgcn_sched_barrier(0);
    }
    sb = cur;
    cur = (cur == 2) ? 0 : cur + 1;
  }

  // ---- epilogue: combine partner half's row-sum, normalize, write O[q][d]
  const float ltot = lrow + __shfl_xor(lrow, 32, 64);
  const float inv = 1.f / ltot;
  const int bb = bh >> 4, h = bh & 15;
  unsigned short* Ob = jb.O + ((size_t)bb * SEQ + qrow) * DM + h * HDIM;

  auto storeO = [&](const f32x16 oo, int dbase) {
#pragma unroll
    for (int g4 = 0; g4 < 4; ++g4) {
      ushort4 pv;
      pv.x = f2bf(oo[4 * g4 + 0] * inv);
      pv.y = f2bf(oo[4 * g4 + 1] * inv);
      pv.z = f2bf(oo[4 * g4 + 2] * inv);
      pv.w = f2bf(oo[4 * g4 + 3] * inv);
      *(ushort4*)(Ob + dbase + 8 * g4 + 4 * hi) = pv;  // d = dbase+8*g4+4*hi+i
    }
  };
  storeO(o0, 0);
  storeO(o1, 32);
}

// ---------------------------------------------------------------- launch
extern "C" void kernel_launch(void* const* d_in, const int* in_sizes, int n_in,
                              void* d_out, int out_size, void* d_ws, size_t ws_size,
                              hipStream_t stream) {
  const float* vis = (const float*)d_in[0];
  const float* inff = (const float*)d_in[1];

  unsigned short* xbf  = (unsigned short*)d_ws;        // [2][4096][1024] bf16
  unsigned short* wt   = xbf + 2 * XSZ;                // 8 x [1024][1024] bf16 (transposed)
  unsigned short* Qv   = wt + (size_t)8 * 1024 * 1024; // each [B*H, S, HD]
  unsigned short* Kv   = Qv + XSZ;
  unsigned short* Vv   = Kv + XSZ;                     // (unused)
  unsigned short* Qi   = Vv + XSZ;
  unsigned short* Ki   = Qi + XSZ;
  unsigned short* Vi   = Ki + XSZ;                     // (unused)
  unsigned short* Vvt  = Vi + XSZ;                     // [B*H, HD, S] written by GEMM mode2
  unsigned short* Vit  = Vvt + XSZ;
  unsigned short* atA  = Vit + XSZ;                    // softmax(Qv Ki^T) Vi, [B,S,D]
  unsigned short* atB  = atA + XSZ;                    // softmax(Qi Kv^T) Vv

  k_convert_x<<<dim3(2048, 1, 2), 256, 0, stream>>>(vis, inff, xbf);

  WPtrs wp;
  wp.w[0] = (const float*)d_in[2];  wp.w[1] = (const float*)d_in[4];
  wp.w[2] = (const float*)d_in[6];  wp.w[3] = (const float*)d_in[8];
  wp.w[4] = (const float*)d_in[10]; wp.w[5] = (const float*)d_in[12];
  wp.w[6] = (const float*)d_in[14]; wp.w[7] = (const float*)d_in[16];
  k_convert_w<<<dim3(16, 16, 8), 256, 0, stream>>>(wp, wt);

  const size_t WSZ = (size_t)1024 * 1024;
  const float qsc = 0.18033688011f;  // log2(e)/8 -> softmax in base-2 domain
  GemmJobs pj;
  pj.j[0] = { xbf,       wt + 0 * WSZ, (const float*)d_in[3],  (void*)Qv,  qsc, 0 };
  pj.j[1] = { xbf,       wt + 1 * WSZ, (const float*)d_in[5],  (void*)Kv,  1.f, 0 };
  pj.j[2] = { xbf,       wt + 2 * WSZ, (const float*)d_in[7],  (void*)Vvt, 1.f, 2 };
  pj.j[3] = { xbf + XSZ, wt + 3 * WSZ, (const float*)d_in[9],  (void*)Qi,  qsc, 0 };
  pj.j[4] = { xbf + XSZ, wt + 4 * WSZ, (const float*)d_in[11], (void*)Ki,  1.f, 0 };
  pj.j[5] = { xbf + XSZ, wt + 5 * WSZ, (const float*)d_in[13], (void*)Vit, 1.f, 2 };
  k_gemm<<<dim3(8, 32, 6), 256, 0, stream>>>(pj);

  AttnJobs aj;
  aj.j[0] = { Qv, Ki, Vit, atA };  // vis queries over inf K/V -> out_inf path
  aj.j[1] = { Qi, Kv, Vvt, atB };  // inf queries over vis K/V -> out_vis path
  k_attn<<<dim3(8, 32, 2), 512, 0, stream>>>(aj);

  GemmJobs oj;
  oj.j[0] = { atB, wt + 6 * WSZ, (const float*)d_in[15], d_out, 1.f, 1 };                      // out_vis
  oj.j[1] = { atA, wt + 7 * WSZ, (const float*)d_in[17], (void*)((float*)d_out + XSZ), 1.f, 1 }; // out_inf
  for (int z = 2; z < 6; ++z) oj.j[z] = oj.j[0];  // unused slots
  k_gemm<<<dim3(8, 32, 2), 256, 0, stream>>>(oj);
}